// Round 3
// baseline (198.071 us; speedup 1.0000x reference)
//
#include <hip/hip_runtime.h>
#include <hip/hip_bf16.h>
#include <math.h>

#define NHEADS 16
#define DKH 64
#define SEQ 2048
#define DMODEL 1024

typedef __attribute__((ext_vector_type(8))) short short8;
typedef __attribute__((ext_vector_type(4))) float f32x4;

// async global->LDS, 16B per lane. LDS dest = wave-uniform base + lane*16.
#define GLDS16(g, l)                                         \
  __builtin_amdgcn_global_load_lds(                          \
      (__attribute__((address_space(1))) void*)(void*)(g),   \
      (__attribute__((address_space(3))) void*)(l), 16, 0, 0)

__device__ __forceinline__ short f2bf(float f) {
  unsigned u = __float_as_uint(f);
  unsigned r = (u + 0x7fffu + ((u >> 16) & 1u)) >> 16;
  return (short)r;
}

// packed f32x2 -> bf16x2 in one instruction (RNE on gfx950; T12 recipe).
// D[15:0] = bf16(lo), D[31:16] = bf16(hi).
__device__ __forceinline__ unsigned cvtpk(float lo, float hi) {
  unsigned r;
  asm("v_cvt_pk_bf16_f32 %0, %1, %2" : "=v"(r) : "v"(lo), "v"(hi));
  return r;
}

__device__ __forceinline__ short8 pack8(float4 a, float4 b) {
  short8 v;
  v[0] = f2bf(a.x); v[1] = f2bf(a.y); v[2] = f2bf(a.z); v[3] = f2bf(a.w);
  v[4] = f2bf(b.x); v[5] = f2bf(b.y); v[6] = f2bf(b.z); v[7] = f2bf(b.w);
  return v;
}

// Swizzled LDS tile [rows][64] bf16. Granule = 8 elems (16B).
// Slot gs of row r holds global granule gs ^ (r&7).
__device__ __forceinline__ int swz(int r, int gran) {
  return r * 64 + ((gran ^ (r & 7)) << 3);
}

// ---------------- precast fp32 -> bf16 + RoPE table (merged) ----------------
__global__ __launch_bounds__(256) void precast_rope_kernel(
    const float* __restrict__ X, const float* __restrict__ Wq,
    const float* __restrict__ Wk, const float* __restrict__ Wv,
    const float* __restrict__ Wo, const int* __restrict__ tp,
    short* __restrict__ Xb, short* __restrict__ Wqb, short* __restrict__ Wkb,
    short* __restrict__ Wvb, short* __restrict__ Wob,
    float* __restrict__ ct, float* __restrict__ st) {
  int bid = blockIdx.x;
  if (bid < 4096) {
    int i = bid * 256 + threadIdx.x;
    const float* src; short* dst; int off;
    if (i < 524288) { src = X; dst = Xb; off = i; }
    else {
      int k = i - 524288; int w = k >> 17; off = k & 131071;
      src = (w == 0) ? Wq : (w == 1) ? Wk : (w == 2) ? Wv : Wo;
      dst = (w == 0) ? Wqb : (w == 1) ? Wkb : (w == 2) ? Wvb : Wob;
    }
    const float4* p = reinterpret_cast<const float4*>(src) + 2 * (size_t)off;
    float4 a = p[0], b = p[1];
    reinterpret_cast<short8*>(dst)[off] = pack8(a, b);
  } else {
    int idx = (bid - 4096) * 256 + threadIdx.x;
    if (idx >= SEQ * 32) return;
    int s = idx >> 5, i = idx & 31;
    int is64 = (tp[1] == 0);
    int p = is64 ? tp[2 * s] : tp[s];
    float invf = powf(10000.0f, -(2.0f * (float)i) / 64.0f);
    float a = (float)p * invf;
    ct[idx] = cosf(a);
    st[idx] = sinf(a);
  }
}

// ---------------- fused QKV projection + RoPE -------------------------------
// Round 10: 256x192 tile -> grid 16x16 = 256 blocks = EXACTLY 1 block/CU.
// B = concatenated [Wq;Wk;Wv] as one 3072x1024 matrix; Q/K/V split in epilogue.
// 8-wave (2x4), per-wave 128x48. LDS 112 KiB double-buffered.
// 4 phases/K-tile; steady-state wait = vmcnt(5) once per K-tile.
// Q,K stored (B,H,S,64) with RoPE applied; V stored TRANSPOSED (B,H,64,S).
__global__ __launch_bounds__(512, 2) void gemm_qkv_kernel(
    const short* __restrict__ X, const short* __restrict__ Wq,
    const short* __restrict__ Wk, const short* __restrict__ Wv,
    short* __restrict__ Qb, short* __restrict__ Kb, short* __restrict__ Vb,
    const float* __restrict__ ct, const float* __restrict__ st) {
  __shared__ __align__(16) short As[2][256 * 64];   // 64 KiB
  __shared__ __align__(16) short Bs[2][192 * 64];   // 48 KiB
  const int id = blockIdx.x;
  // XCD-chunked 2D swizzle: xcd = id&7 (round-robin dispatch assumption),
  // each XCD gets a 4(tm) x 8(tn) region. Bijective over 16x16.
  const int xcd = id & 7, rr = id >> 3;
  const int tm = (xcd & 3) * 4 + (rr & 3);
  const int tn = (xcd >> 2) * 8 + (rr >> 2);
  const int tid = threadIdx.x;
  const int wave = tid >> 6, lane = tid & 63;
  const int l15 = lane & 15, quad = lane >> 4;
  const int wm = wave >> 2, wn = wave & 3;   // 2x4 wave grid, 128x48 each

  const int n0 = tn * 192;                   // col in concat [Wq;Wk;Wv]
  const short* Abase = X + (size_t)(tm * 256) * DMODEL;
  const short* Bbase = Wq + (size_t)n0 * DMODEL;   // Wq,Wk,Wv contiguous
  (void)Wk; (void)Wv;

  const int lr = lane >> 3;            // row within 8-row chunk
  const int lc = (lane & 7) ^ lr;      // XOR-permuted source granule

  // A half-tile = 128 rows x 64 k: 2 GLDS/wave (16 rows/wave).
#define STGA(bufi, half, kt_)                                              \
  do {                                                                     \
    int R0 = (half) * 128 + wave * 16;                                     \
    GLDS16(Abase + (size_t)(R0 + lr) * DMODEL + (kt_) * 64 + lc * 8,       \
           &As[bufi][R0 * 64 + lane * 8]);                                 \
    GLDS16(Abase + (size_t)(R0 + 8 + lr) * DMODEL + (kt_) * 64 + lc * 8,   \
           &As[bufi][(R0 + 8) * 64 + lane * 8]);                           \
  } while (0)
  // B third = 64 rows x 64 k: 1 GLDS/wave (8 rows/wave).
#define STGB(bufi, t, kt_)                                                 \
  do {                                                                     \
    int R0 = (t) * 64 + wave * 8;                                          \
    GLDS16(Bbase + (size_t)(R0 + lr) * DMODEL + (kt_) * 64 + lc * 8,       \
           &Bs[bufi][R0 * 64 + lane * 8]);                                 \
  } while (0)

  f32x4 acc[8][3];
#pragma unroll
  for (int m = 0; m < 8; m++)
#pragma unroll
    for (int n = 0; n < 3; n++) acc[m][n] = (f32x4){0.f, 0.f, 0.f, 0.f};

  // prologue: B(0)[3], A0(0)[2], A1(0)[2], B(1)[3] = 10 in flight.
  STGB(0, 0, 0); STGB(0, 1, 0); STGB(0, 2, 0);
  STGA(0, 0, 0); STGA(0, 1, 0);
  STGB(1, 0, 1); STGB(1, 1, 1); STGB(1, 2, 1);

  short8 bfr[3][2];   // B frags live for a whole K-tile (read in phase 0)
  for (int kt = 0; kt < 16; kt++) {
    const int buf = kt & 1;
    // ---- phase 0: stage A-half0(kt+1); wait kt's data; B frags + mf 0,1 ----
    if (kt < 15) { STGA(buf ^ 1, 0, kt + 1); }
    if (kt < 15) { asm volatile("s_waitcnt vmcnt(5)" ::: "memory"); }
    else         { asm volatile("s_waitcnt vmcnt(0)" ::: "memory"); }
    asm volatile("s_barrier" ::: "memory");
#pragma unroll
    for (int nb = 0; nb < 3; nb++)
#pragma unroll
      for (int ks = 0; ks < 2; ks++)
        bfr[nb][ks] = *reinterpret_cast<const short8*>(
            &Bs[buf][swz(wn * 48 + nb * 16 + l15, ks * 4 + quad)]);
    {
      short8 af[2][2];
#pragma unroll
      for (int j = 0; j < 2; j++)
#pragma unroll
        for (int ks = 0; ks < 2; ks++)
          af[j][ks] = *reinterpret_cast<const short8*>(
              &As[buf][swz(wm * 128 + j * 16 + l15, ks * 4 + quad)]);
      __builtin_amdgcn_s_setprio(1);
#pragma unroll
      for (int j = 0; j < 2; j++)
#pragma unroll
        for (int nb = 0; nb < 3; nb++)
#pragma unroll
          for (int ks = 0; ks < 2; ks++)
            acc[j][nb] = __builtin_amdgcn_mfma_f32_16x16x32_bf16(
                af[j][ks], bfr[nb][ks], acc[j][nb], 0, 0, 0);
      __builtin_amdgcn_s_setprio(0);
    }
    asm volatile("s_barrier" ::: "memory");
    // ---- phases 1..3: A frags mf {2p,2p+1}; stage per schedule ------------
#pragma unroll
    for (int p = 1; p < 4; p++) {
      short8 af[2][2];
#pragma unroll
      for (int j = 0; j < 2; j++)
#pragma unroll
        for (int ks = 0; ks < 2; ks++)
          af[j][ks] = *reinterpret_cast<const short8*>(
              &As[buf][swz(wm * 128 + (p * 2 + j) * 16 + l15, ks * 4 + quad)]);
      if (p == 1)      { if (kt < 15) { STGA(buf ^ 1, 1, kt + 1); } }
      else if (p == 2) { if (kt < 14) { STGB(buf, 0, kt + 2); STGB(buf, 1, kt + 2); } }
      else             { if (kt < 14) { STGB(buf, 2, kt + 2); } }
      asm volatile("s_barrier" ::: "memory");
      __builtin_amdgcn_s_setprio(1);
#pragma unroll
      for (int j = 0; j < 2; j++)
#pragma unroll
        for (int nb = 0; nb < 3; nb++)
#pragma unroll
          for (int ks = 0; ks < 2; ks++)
            acc[p * 2 + j][nb] = __builtin_amdgcn_mfma_f32_16x16x32_bf16(
                af[j][ks], bfr[nb][ks], acc[p * 2 + j][nb], 0, 0, 0);
      __builtin_amdgcn_s_setprio(0);
      asm volatile("s_barrier" ::: "memory");
    }
  }
#undef STGA
#undef STGB

  // epilogue: nl is a col of concat [Wq;Wk;Wv]; mid = nl>>10 picks the matrix
#pragma unroll
  for (int mf = 0; mf < 8; mf++) {
    const int s0g = tm * 256 + wm * 128 + mf * 16 + quad * 4;   // rows
    const int b = s0g >> 11, s = s0g & 2047;
#pragma unroll
    for (int nb = 0; nb < 3; nb++) {
      int nl = n0 + wn * 48 + nb * 16 + l15;
      int mid = nl >> 10;                 // 0=Q 1=K 2=V
      int c = nl & 1023;
      int h = c >> 6, dd = c & 63;
      if (mid == 2) {
        // V: packed b64 transposed store -> Vb[(b,h)][dd][s..s+3]
        unsigned u0 = (unsigned)(unsigned short)f2bf(acc[mf][nb][0]) |
                      ((unsigned)(unsigned short)f2bf(acc[mf][nb][1]) << 16);
        unsigned u1 = (unsigned)(unsigned short)f2bf(acc[mf][nb][2]) |
                      ((unsigned)(unsigned short)f2bf(acc[mf][nb][3]) << 16);
        uint2 pk; pk.x = u0; pk.y = u1;
        *reinterpret_cast<uint2*>(Vb + ((size_t)(b * NHEADS + h) * DKH + dd) * SEQ + s) = pk;
      } else {
#pragma unroll
        for (int reg = 0; reg < 4; reg++) {
          float v = acc[mf][nb][reg];
          float pv = __shfl_xor(v, 1);
          int fi = dd >> 1;
          int sg = s + reg;
          float cc = ct[sg * 32 + fi], sn = st[sg * 32 + fi];
          float o = (dd & 1) ? (pv * sn + v * cc) : (v * cc - pv * sn);
          size_t oi = (((size_t)(b * NHEADS + h)) * SEQ + sg) * DKH + dd;
          ((mid == 0) ? Qb : Kb)[oi] = f2bf(o);
        }
      }
    }
  }
}

// ---------------- flash attention (causal), round 11 ------------------------
// Round-8 S^T scheme + this round's changes:
//  (1) P pack via v_cvt_pk_bf16_f32 (2 f32 -> 1 u32, RNE) -- was 16x manual
//      f2bf + shifts/ors (~70 VALU ops/kt removed).
//  (2) XCD-aware bh grouping: id&7 = XCD slot, 4 consecutive bh per XCD ->
//      K/V+Q L2 footprint ~3MB < 4MB per-XCD L2 (was: each bh fetched by all
//      8 XCDs -> 71MB HBM fetch). qt interleaved big/small for causal balance.
//  (3) s_setprio(1) around QK and PV MFMA clusters (T5; m191 attn-positive).
//  (4) barrier between qf read and first P overwrite of QPs (closes a
//      pre-existing race window).
__global__ __launch_bounds__(256, 4) void attn_kernel(
    const short* __restrict__ Qb, const short* __restrict__ Kb,
    const short* __restrict__ Vtb, short* __restrict__ Ob) {
  __shared__ __align__(16) short QPs[64 * 64];     // Q staging, then P tiles
  __shared__ __align__(16) short Ks[2][64 * 64];   // [key][d]
  __shared__ __align__(16) short Vs[2][64 * 64];   // [dv][key] (from Vtb rows)

  const int id = blockIdx.x;
  const int x8 = id & 7;               // XCD slot (round-robin dispatch)
  const int g  = id >> 3;              // 0..127
  const int bh = x8 * 4 + (g >> 5);    // 4 consecutive bh per XCD
  const int u  = g & 31;
  const int qt = (u & 1) ? (31 - (u >> 1)) : (u >> 1);   // big/small pairs

  const int tid = threadIdx.x;
  const int wave = tid >> 6, lane = tid & 63;
  const int l15 = lane & 15, quad = lane >> 4;
  const int sr0 = tid >> 3, sc = tid & 7;

  const short* Qp = Qb + (size_t)bh * SEQ * DKH;
  const short* Kp = Kb + (size_t)bh * SEQ * DKH;
  const short* Vp = Vtb + (size_t)bh * DKH * SEQ;  // rows = dv, cols = s

  uint4 kreg[2], vreg[2];
#pragma unroll
  for (int i = 0; i < 2; i++) {
    int r = sr0 + i * 32;
    kreg[i] = *reinterpret_cast<const uint4*>(Kp + (size_t)r * DKH + sc * 8);
    vreg[i] = *reinterpret_cast<const uint4*>(Vp + (size_t)r * SEQ + sc * 8);
  }
#pragma unroll
  for (int i = 0; i < 2; i++) {
    int r = sr0 + i * 32;
    uint4 v = *reinterpret_cast<const uint4*>(Qp + (size_t)(qt * 64 + r) * DKH + sc * 8);
    *reinterpret_cast<uint4*>(&QPs[swz(r, sc)]) = v;
  }
#pragma unroll
  for (int i = 0; i < 2; i++) {
    int r = sr0 + i * 32;
    *reinterpret_cast<uint4*>(&Ks[0][swz(r, sc)]) = kreg[i];
    *reinterpret_cast<uint4*>(&Vs[0][swz(r, sc)]) = vreg[i];
  }
  __syncthreads();
  short8 qf0, qf1;
  {
    int r = wave * 16 + l15;
    qf0 = *reinterpret_cast<const short8*>(&QPs[swz(r, quad)]);
    qf1 = *reinterpret_cast<const short8*>(&QPs[swz(r, 4 + quad)]);
  }
  __syncthreads();   // all waves done reading Q before P overwrites QPs

  f32x4 accO[4];
#pragma unroll
  for (int i = 0; i < 4; i++) accO[i] = (f32x4){0.f, 0.f, 0.f, 0.f};
  float rs = 0.f;   // partial row-sum for q-row (wave*16+l15), this lane's keys

  const float SCL = 0.125f * 1.44269504089f;   // 1/sqrt(64) * log2(e)
  const float FM = 13.0f;                      // fixed softmax shift (exact)

  int buf = 0;
  for (int kt = 0; kt <= qt; kt++) {
    if (kt < qt) {
#pragma unroll
      for (int i = 0; i < 2; i++) {
        int r = sr0 + i * 32;
        kreg[i] = *reinterpret_cast<const uint4*>(Kp + (size_t)((kt + 1) * 64 + r) * DKH + sc * 8);
        vreg[i] = *reinterpret_cast<const uint4*>(Vp + (size_t)r * SEQ + (kt + 1) * 64 + sc * 8);
      }
    }

    // S^T = K Q^T : D[m=key][n=qrow]; lane holds keys nb*16+quad*4+{0..3},
    // q-row = wave*16+l15.
    f32x4 sa[4];
    __builtin_amdgcn_s_setprio(1);
#pragma unroll
    for (int nb = 0; nb < 4; nb++) {
      sa[nb] = (f32x4){0.f, 0.f, 0.f, 0.f};
      int r = nb * 16 + l15;
      short8 kf0 = *reinterpret_cast<const short8*>(&Ks[buf][swz(r, quad)]);
      sa[nb] = __builtin_amdgcn_mfma_f32_16x16x32_bf16(kf0, qf0, sa[nb], 0, 0, 0);
      short8 kf1 = *reinterpret_cast<const short8*>(&Ks[buf][swz(r, 4 + quad)]);
      sa[nb] = __builtin_amdgcn_mfma_f32_16x16x32_bf16(kf1, qf1, sa[nb], 0, 0, 0);
    }
    __builtin_amdgcn_s_setprio(0);

    const bool diag = (kt == qt);
    const int prow = wave * 16 + l15;          // this lane's q-row (P row)
#pragma unroll
    for (int nb = 0; nb < 4; nb++) {
      float p0 = exp2f(sa[nb][0] * SCL - FM);
      float p1 = exp2f(sa[nb][1] * SCL - FM);
      float p2 = exp2f(sa[nb][2] * SCL - FM);
      float p3 = exp2f(sa[nb][3] * SCL - FM);
      if (diag) {
        int kbase = nb * 16 + quad * 4;
        if (kbase + 0 > prow) p0 = 0.f;
        if (kbase + 1 > prow) p1 = 0.f;
        if (kbase + 2 > prow) p2 = 0.f;
        if (kbase + 3 > prow) p3 = 0.f;
      }
      rs += (p0 + p1) + (p2 + p3);
      uint2 pk; pk.x = cvtpk(p0, p1); pk.y = cvtpk(p2, p3);
      int g2 = 2 * nb + (quad >> 1);           // granule of keys 16nb+8*(q>>1)
      *reinterpret_cast<uint2*>(&QPs[swz(prow, g2) + (quad & 1) * 4]) = pk;
    }

    // O += P V : A = P (row=qrow=l15, keys u*32+quad*8+..), B = V^T rows
    short8 pf0 = *reinterpret_cast<const short8*>(&QPs[swz(prow, quad)]);
    short8 pf1 = *reinterpret_cast<const short8*>(&QPs[swz(prow, 4 + quad)]);
    __builtin_amdgcn_s_setprio(1);
#pragma unroll
    for (int db = 0; db < 4; db++) {
      int dv = db * 16 + l15;
      short8 vf0 = *reinterpret_cast<const short8*>(&Vs[buf][swz(dv, quad)]);
      accO[db] = __builtin_amdgcn_mfma_f32_16x16x32_bf16(pf0, vf0, accO[db], 0, 0, 0);
      short8 vf1 = *reinterpret_cast<const short8*>(&Vs[buf][swz(dv, 4 + quad)]);
      accO[db] = __builtin_amdgcn_mfma_f32_16x16x32_bf16(pf1, vf1, accO[db], 0, 0, 0);
    }
    __builtin_amdgcn_s_setprio(0);

    if (kt < qt) {
      int nbuf = buf ^ 1;
#pragma unroll
      for (int i = 0; i < 2; i++) {
        int r = sr0 + i * 32;
        *reinterpret_cast<uint4*>(&Ks[nbuf][swz(r, sc)]) = kreg[i];
        *reinterpret_cast<uint4*>(&Vs[nbuf][swz(r, sc)]) = vreg[i];
      }
      __syncthreads();
      buf = nbuf;
    }
  }

  // reduce rs across the 4 quads sharing each l15 (full row sum)
  float t = rs;
  t += __shfl_xor(t, 16);
  t += __shfl_xor(t, 32);
  // accO rows are qrow = quad*4+reg; fetch lrow from lane l15 = quad*4+reg
  float lv[4];
#pragma unroll
  for (int reg = 0; reg < 4; reg++) lv[reg] = __shfl(t, quad * 4 + reg);

  // write (B,S,1024) bf16
  int b = bh >> 4, h = bh & 15;
#pragma unroll
  for (int db = 0; db < 4; db++)
#pragma unroll
    for (int reg = 0; reg < 4; reg++) {
      int s = qt * 64 + wave * 16 + quad * 4 + reg;
      int dv = db * 16 + l15;
      float o = accO[db][reg] / lv[reg];
      Ob[((size_t)(b * SEQ + s)) * DMODEL + h * DKH + dv] = f2bf(o);
    }
}

// ---------------- output projection, 128x64 tile + GLDS (fp32 output) -------
__global__ __launch_bounds__(256) void gemm_out_kernel(
    const short* __restrict__ X, const short* __restrict__ Wo, float* __restrict__ Out) {
  __shared__ __align__(16) short As[128 * 64];
  __shared__ __align__(16) short Bs[64 * 64];
  const int tm = blockIdx.x;   // 32 (M tiles of 128)
  const int tn = blockIdx.y;   // 16 (N tiles of 64)
  const int tid = threadIdx.x;
  const int wave = tid >> 6, lane = tid & 63;
  const int l15 = lane & 15, quad = lane >> 4;
  const int wm = wave >> 1, wn = wave & 1;   // wave tile 64M x 32N

  const short* Abase = X + (size_t)(tm * 128) * DMODEL;
  const short* Bbase = Wo + (size_t)(tn * 64) * DMODEL;

  const int lr = lane >> 3;
  const int lc = (lane & 7) ^ lr;

  f32x4 acc[4][2];
#pragma unroll
  for (int mb = 0; mb < 4; mb++)
#pragma unroll
    for (int nb = 0; nb < 2; nb++) acc[mb][nb] = (f32x4){0.f, 0.f, 0.f, 0.f};

  for (int kk = 0; kk < 16; kk++) {
    const short* Ak = Abase + kk * 64;
    const short* Bk = Bbase + kk * 64;
#pragma unroll
    for (int i = 0; i < 4; i++) {
      int R = i * 32 + wave * 8;
      GLDS16(Ak + (size_t)(R + lr) * DMODEL + lc * 8, &As[R * 64 + lane * 8]);
    }
#pragma unroll
    for (int i = 0; i < 2; i++) {
      int R = i * 32 + wave * 8;
      GLDS16(Bk + (size_t)(R + lr) * DMODEL + lc * 8, &Bs[R * 64 + lane * 8]);
    }
    __syncthreads();
#pragma unroll
    for (int kg = 0; kg < 2; kg++) {
      short8 af[4], bf[2];
#pragma unroll
      for (int mb = 0; mb < 4; mb++) {
        int r = wm * 64 + mb * 16 + l15;
        af[mb] = *reinterpret_cast<const short8*>(&As[swz(r, kg * 4 + quad)]);
      }
#pragma unroll
      for (int nb = 0; nb < 2; nb++) {
        int r = wn * 32 + nb * 16 + l15;
        bf[nb] = *reinterpret_cast<const short8*>(&Bs[swz(r, kg * 4 + quad)]);
      }
#pragma unroll
      for (int mb = 0; mb < 4; mb++)
#pragma unroll
        for (int nb = 0; nb < 2; nb++)
          acc[mb][nb] = __builtin_amdgcn_mfma_f32_16x16x32_bf16(af[mb], bf[nb], acc[mb][nb], 0, 0, 0);
    }
    __syncthreads();
  }
#pragma unroll
  for (int mb = 0; mb < 4; mb++)
#pragma unroll
    for (int nb = 0; nb < 2; nb++)
#pragma unroll
      for (int reg = 0; reg < 4; reg++) {
        int rg = tm * 128 + wm * 64 + mb * 16 + quad * 4 + reg;
        int col = tn * 64 + wn * 32 + nb * 16 + l15;
        Out[(size_t)rg * DMODEL + col] = acc[mb][nb][reg];
      }
}

extern "C" void kernel_launch(void* const* d_in, const int* in_sizes, int n_in,
                              void* d_out, int out_size, void* d_ws, size_t ws_size,
                              hipStream_t stream) {
  (void)in_sizes; (void)n_in; (void)out_size; (void)ws_size;
  const float* X  = (const float*)d_in[0];
  const int*   tp = (const int*)d_in[1];
  const float* Wq = (const float*)d_in[2];
  const float* Wk = (const float*)d_in[3];
  const float* Wv = (const float*)d_in[4];
  const float* Wo = (const float*)d_in[5];
  float* Out = (float*)d_out;

  short* Qb  = (short*)d_ws;           // 4M shorts each
  short* Kb  = Qb + 4194304;
  short* Vb  = Kb + 4194304;           // holds V^T (B,H,D,S)
  short* Ab  = Vb + 4194304;
  short* Xb  = Ab + 4194304;           // 4M
  short* Wqb = Xb + 4194304;           // 1M each; Wqb,Wkb,Wvb CONTIGUOUS
  short* Wkb = Wqb + 1048576;          //   (gemm_qkv treats them as one
  short* Wvb = Wkb + 1048576;          //    3072x1024 concatenated B matrix)
  short* Wob = Wvb + 1048576;
  float* ct  = (float*)(Wob + 1048576);
  float* st  = ct + SEQ * 32;

  precast_rope_kernel<<<dim3(4352), dim3(256), 0, stream>>>(
      X, Wq, Wk, Wv, Wo, tp, Xb, Wqb, Wkb, Wvb, Wob, ct, st);
  gemm_qkv_kernel<<<dim3(256), dim3(512), 0, stream>>>(Xb, Wqb, Wkb, Wvb,
                                                       Qb, Kb, Vb, ct, st);
  attn_kernel<<<dim3(1024), dim3(256), 0, stream>>>(Qb, Kb, Vb, Ab);
  gemm_out_kernel<<<dim3(32, 16), dim3(256), 0, stream>>>(Ab, Wob, Out);
}

// Round 4
// 185.937 us; speedup vs baseline: 1.0653x; 1.0653x over previous
//
#include <hip/hip_runtime.h>
#include <hip/hip_bf16.h>
#include <math.h>

#define NHEADS 16
#define DKH 64
#define SEQ 2048
#define DMODEL 1024

typedef __attribute__((ext_vector_type(8))) short short8;
typedef __attribute__((ext_vector_type(4))) float f32x4;

// async global->LDS, 16B per lane. LDS dest = wave-uniform base + lane*16.
#define GLDS16(g, l)                                         \
  __builtin_amdgcn_global_load_lds(                          \
      (__attribute__((address_space(1))) void*)(void*)(g),   \
      (__attribute__((address_space(3))) void*)(l), 16, 0, 0)

__device__ __forceinline__ short f2bf(float f) {
  unsigned u = __float_as_uint(f);
  unsigned r = (u + 0x7fffu + ((u >> 16) & 1u)) >> 16;
  return (short)r;
}

// packed f32x2 -> bf16x2 in one instruction (RNE on gfx950; T12 recipe).
// D[15:0] = bf16(lo), D[31:16] = bf16(hi).
__device__ __forceinline__ unsigned cvtpk(float lo, float hi) {
  unsigned r;
  asm("v_cvt_pk_bf16_f32 %0, %1, %2" : "=v"(r) : "v"(lo), "v"(hi));
  return r;
}

__device__ __forceinline__ short8 pack8(float4 a, float4 b) {
  short8 v;
  v[0] = f2bf(a.x); v[1] = f2bf(a.y); v[2] = f2bf(a.z); v[3] = f2bf(a.w);
  v[4] = f2bf(b.x); v[5] = f2bf(b.y); v[6] = f2bf(b.z); v[7] = f2bf(b.w);
  return v;
}

// Swizzled LDS tile [rows][64] bf16. Granule = 8 elems (16B).
// Slot gs of row r holds global granule gs ^ (r&7).
__device__ __forceinline__ int swz(int r, int gran) {
  return r * 64 + ((gran ^ (r & 7)) << 3);
}

// ---------------- precast fp32 -> bf16 + RoPE table (merged) ----------------
__global__ __launch_bounds__(256) void precast_rope_kernel(
    const float* __restrict__ X, const float* __restrict__ Wq,
    const float* __restrict__ Wk, const float* __restrict__ Wv,
    const float* __restrict__ Wo, const int* __restrict__ tp,
    short* __restrict__ Xb, short* __restrict__ Wqb, short* __restrict__ Wkb,
    short* __restrict__ Wvb, short* __restrict__ Wob,
    float* __restrict__ ct, float* __restrict__ st) {
  int bid = blockIdx.x;
  if (bid < 4096) {
    int i = bid * 256 + threadIdx.x;
    const float* src; short* dst; int off;
    if (i < 524288) { src = X; dst = Xb; off = i; }
    else {
      int k = i - 524288; int w = k >> 17; off = k & 131071;
      src = (w == 0) ? Wq : (w == 1) ? Wk : (w == 2) ? Wv : Wo;
      dst = (w == 0) ? Wqb : (w == 1) ? Wkb : (w == 2) ? Wvb : Wob;
    }
    const float4* p = reinterpret_cast<const float4*>(src) + 2 * (size_t)off;
    float4 a = p[0], b = p[1];
    reinterpret_cast<short8*>(dst)[off] = pack8(a, b);
  } else {
    int idx = (bid - 4096) * 256 + threadIdx.x;
    if (idx >= SEQ * 32) return;
    int s = idx >> 5, i = idx & 31;
    int is64 = (tp[1] == 0);
    int p = is64 ? tp[2 * s] : tp[s];
    float invf = powf(10000.0f, -(2.0f * (float)i) / 64.0f);
    float a = (float)p * invf;
    ct[idx] = cosf(a);
    st[idx] = sinf(a);
  }
}

// ---------------- fused QKV projection + RoPE -------------------------------
// Round 10: 256x192 tile -> grid 16x16 = 256 blocks = EXACTLY 1 block/CU.
// B = concatenated [Wq;Wk;Wv] as one 3072x1024 matrix; Q/K/V split in epilogue.
// 8-wave (2x4), per-wave 128x48. LDS 112 KiB double-buffered.
// 4 phases/K-tile; steady-state wait = vmcnt(5) once per K-tile.
// Q,K stored (B,H,S,64) with RoPE applied; V stored TRANSPOSED (B,H,64,S).
__global__ __launch_bounds__(512, 2) void gemm_qkv_kernel(
    const short* __restrict__ X, const short* __restrict__ Wq,
    const short* __restrict__ Wk, const short* __restrict__ Wv,
    short* __restrict__ Qb, short* __restrict__ Kb, short* __restrict__ Vb,
    const float* __restrict__ ct, const float* __restrict__ st) {
  __shared__ __align__(16) short As[2][256 * 64];   // 64 KiB
  __shared__ __align__(16) short Bs[2][192 * 64];   // 48 KiB
  const int id = blockIdx.x;
  // XCD-chunked 2D swizzle: xcd = id&7 (round-robin dispatch assumption),
  // each XCD gets a 4(tm) x 8(tn) region. Bijective over 16x16.
  const int xcd = id & 7, rr = id >> 3;
  const int tm = (xcd & 3) * 4 + (rr & 3);
  const int tn = (xcd >> 2) * 8 + (rr >> 2);
  const int tid = threadIdx.x;
  const int wave = tid >> 6, lane = tid & 63;
  const int l15 = lane & 15, quad = lane >> 4;
  const int wm = wave >> 2, wn = wave & 3;   // 2x4 wave grid, 128x48 each

  const int n0 = tn * 192;                   // col in concat [Wq;Wk;Wv]
  const short* Abase = X + (size_t)(tm * 256) * DMODEL;
  const short* Bbase = Wq + (size_t)n0 * DMODEL;   // Wq,Wk,Wv contiguous
  (void)Wk; (void)Wv;

  const int lr = lane >> 3;            // row within 8-row chunk
  const int lc = (lane & 7) ^ lr;      // XOR-permuted source granule

  // A half-tile = 128 rows x 64 k: 2 GLDS/wave (16 rows/wave).
#define STGA(bufi, half, kt_)                                              \
  do {                                                                     \
    int R0 = (half) * 128 + wave * 16;                                     \
    GLDS16(Abase + (size_t)(R0 + lr) * DMODEL + (kt_) * 64 + lc * 8,       \
           &As[bufi][R0 * 64 + lane * 8]);                                 \
    GLDS16(Abase + (size_t)(R0 + 8 + lr) * DMODEL + (kt_) * 64 + lc * 8,   \
           &As[bufi][(R0 + 8) * 64 + lane * 8]);                           \
  } while (0)
  // B third = 64 rows x 64 k: 1 GLDS/wave (8 rows/wave).
#define STGB(bufi, t, kt_)                                                 \
  do {                                                                     \
    int R0 = (t) * 64 + wave * 8;                                          \
    GLDS16(Bbase + (size_t)(R0 + lr) * DMODEL + (kt_) * 64 + lc * 8,       \
           &Bs[bufi][R0 * 64 + lane * 8]);                                 \
  } while (0)

  f32x4 acc[8][3];
#pragma unroll
  for (int m = 0; m < 8; m++)
#pragma unroll
    for (int n = 0; n < 3; n++) acc[m][n] = (f32x4){0.f, 0.f, 0.f, 0.f};

  // prologue: B(0)[3], A0(0)[2], A1(0)[2], B(1)[3] = 10 in flight.
  STGB(0, 0, 0); STGB(0, 1, 0); STGB(0, 2, 0);
  STGA(0, 0, 0); STGA(0, 1, 0);
  STGB(1, 0, 1); STGB(1, 1, 1); STGB(1, 2, 1);

  short8 bfr[3][2];   // B frags live for a whole K-tile (read in phase 0)
  for (int kt = 0; kt < 16; kt++) {
    const int buf = kt & 1;
    // ---- phase 0: stage A-half0(kt+1); wait kt's data; B frags + mf 0,1 ----
    if (kt < 15) { STGA(buf ^ 1, 0, kt + 1); }
    if (kt < 15) { asm volatile("s_waitcnt vmcnt(5)" ::: "memory"); }
    else         { asm volatile("s_waitcnt vmcnt(0)" ::: "memory"); }
    asm volatile("s_barrier" ::: "memory");
#pragma unroll
    for (int nb = 0; nb < 3; nb++)
#pragma unroll
      for (int ks = 0; ks < 2; ks++)
        bfr[nb][ks] = *reinterpret_cast<const short8*>(
            &Bs[buf][swz(wn * 48 + nb * 16 + l15, ks * 4 + quad)]);
    {
      short8 af[2][2];
#pragma unroll
      for (int j = 0; j < 2; j++)
#pragma unroll
        for (int ks = 0; ks < 2; ks++)
          af[j][ks] = *reinterpret_cast<const short8*>(
              &As[buf][swz(wm * 128 + j * 16 + l15, ks * 4 + quad)]);
      __builtin_amdgcn_s_setprio(1);
#pragma unroll
      for (int j = 0; j < 2; j++)
#pragma unroll
        for (int nb = 0; nb < 3; nb++)
#pragma unroll
          for (int ks = 0; ks < 2; ks++)
            acc[j][nb] = __builtin_amdgcn_mfma_f32_16x16x32_bf16(
                af[j][ks], bfr[nb][ks], acc[j][nb], 0, 0, 0);
      __builtin_amdgcn_s_setprio(0);
    }
    asm volatile("s_barrier" ::: "memory");
    // ---- phases 1..3: A frags mf {2p,2p+1}; stage per schedule ------------
#pragma unroll
    for (int p = 1; p < 4; p++) {
      short8 af[2][2];
#pragma unroll
      for (int j = 0; j < 2; j++)
#pragma unroll
        for (int ks = 0; ks < 2; ks++)
          af[j][ks] = *reinterpret_cast<const short8*>(
              &As[buf][swz(wm * 128 + (p * 2 + j) * 16 + l15, ks * 4 + quad)]);
      if (p == 1)      { if (kt < 15) { STGA(buf ^ 1, 1, kt + 1); } }
      else if (p == 2) { if (kt < 14) { STGB(buf, 0, kt + 2); STGB(buf, 1, kt + 2); } }
      else             { if (kt < 14) { STGB(buf, 2, kt + 2); } }
      asm volatile("s_barrier" ::: "memory");
      __builtin_amdgcn_s_setprio(1);
#pragma unroll
      for (int j = 0; j < 2; j++)
#pragma unroll
        for (int nb = 0; nb < 3; nb++)
#pragma unroll
          for (int ks = 0; ks < 2; ks++)
            acc[p * 2 + j][nb] = __builtin_amdgcn_mfma_f32_16x16x32_bf16(
                af[j][ks], bfr[nb][ks], acc[p * 2 + j][nb], 0, 0, 0);
      __builtin_amdgcn_s_setprio(0);
      asm volatile("s_barrier" ::: "memory");
    }
  }
#undef STGA
#undef STGB

  // epilogue: nl is a col of concat [Wq;Wk;Wv]; mid = nl>>10 picks the matrix
#pragma unroll
  for (int mf = 0; mf < 8; mf++) {
    const int s0g = tm * 256 + wm * 128 + mf * 16 + quad * 4;   // rows
    const int b = s0g >> 11, s = s0g & 2047;
#pragma unroll
    for (int nb = 0; nb < 3; nb++) {
      int nl = n0 + wn * 48 + nb * 16 + l15;
      int mid = nl >> 10;                 // 0=Q 1=K 2=V
      int c = nl & 1023;
      int h = c >> 6, dd = c & 63;
      if (mid == 2) {
        // V: packed b64 transposed store -> Vb[(b,h)][dd][s..s+3]
        unsigned u0 = (unsigned)(unsigned short)f2bf(acc[mf][nb][0]) |
                      ((unsigned)(unsigned short)f2bf(acc[mf][nb][1]) << 16);
        unsigned u1 = (unsigned)(unsigned short)f2bf(acc[mf][nb][2]) |
                      ((unsigned)(unsigned short)f2bf(acc[mf][nb][3]) << 16);
        uint2 pk; pk.x = u0; pk.y = u1;
        *reinterpret_cast<uint2*>(Vb + ((size_t)(b * NHEADS + h) * DKH + dd) * SEQ + s) = pk;
      } else {
#pragma unroll
        for (int reg = 0; reg < 4; reg++) {
          float v = acc[mf][nb][reg];
          float pv = __shfl_xor(v, 1);
          int fi = dd >> 1;
          int sg = s + reg;
          float cc = ct[sg * 32 + fi], sn = st[sg * 32 + fi];
          float o = (dd & 1) ? (pv * sn + v * cc) : (v * cc - pv * sn);
          size_t oi = (((size_t)(b * NHEADS + h)) * SEQ + sg) * DKH + dd;
          ((mid == 0) ? Qb : Kb)[oi] = f2bf(o);
        }
      }
    }
  }
}

// ---------------- flash attention (causal), round 12 ------------------------
// Round-11 changes kept (cvt_pk pack, setprio, race-fix barrier, XCD bh
// grouping). Round-12 fix: restore PER-CU LOAD BALANCE that round 11 broke.
// Co-residency model: 4 blocks/CU; block -> {XCD = id&7, CU-slot = (id>>3)&31,
// round = id>>8}. Round 11 gave all 4 co-resident blocks the SAME qt ->
// max-loaded CU ran 4x qt=31 (~2x mean). Now per-round qt maps
// {c, 31-c, (c+16)&31, (15-c)&31}: each is a permutation of 0..31 (bijective
// coverage) and the per-CU sum is 62 for EVERY c (perfect balance).
// bh = xcd*4 + round keeps the ~3MB/XCD L2 footprint (12MB fetch).
__global__ __launch_bounds__(256, 4) void attn_kernel(
    const short* __restrict__ Qb, const short* __restrict__ Kb,
    const short* __restrict__ Vtb, short* __restrict__ Ob) {
  __shared__ __align__(16) short QPs[64 * 64];     // Q staging, then P tiles
  __shared__ __align__(16) short Ks[2][64 * 64];   // [key][d]
  __shared__ __align__(16) short Vs[2][64 * 64];   // [dv][key] (from Vtb rows)

  const int id = blockIdx.x;
  const int x8 = id & 7;               // XCD slot (round-robin dispatch)
  const int c  = (id >> 3) & 31;       // CU slot within XCD
  const int q2 = id >> 8;              // co-residency round (0..3)
  const int bh = x8 * 4 + q2;          // 4 consecutive bh per XCD (L2 local)
  const int qt = (q2 == 0) ? c
               : (q2 == 1) ? (31 - c)
               : (q2 == 2) ? ((c + 16) & 31)
               : ((15 - c) & 31);      // per-CU qt sum = 62 for all c

  const int tid = threadIdx.x;
  const int wave = tid >> 6, lane = tid & 63;
  const int l15 = lane & 15, quad = lane >> 4;
  const int sr0 = tid >> 3, sc = tid & 7;

  const short* Qp = Qb + (size_t)bh * SEQ * DKH;
  const short* Kp = Kb + (size_t)bh * SEQ * DKH;
  const short* Vp = Vtb + (size_t)bh * DKH * SEQ;  // rows = dv, cols = s

  uint4 kreg[2], vreg[2];
#pragma unroll
  for (int i = 0; i < 2; i++) {
    int r = sr0 + i * 32;
    kreg[i] = *reinterpret_cast<const uint4*>(Kp + (size_t)r * DKH + sc * 8);
    vreg[i] = *reinterpret_cast<const uint4*>(Vp + (size_t)r * SEQ + sc * 8);
  }
#pragma unroll
  for (int i = 0; i < 2; i++) {
    int r = sr0 + i * 32;
    uint4 v = *reinterpret_cast<const uint4*>(Qp + (size_t)(qt * 64 + r) * DKH + sc * 8);
    *reinterpret_cast<uint4*>(&QPs[swz(r, sc)]) = v;
  }
#pragma unroll
  for (int i = 0; i < 2; i++) {
    int r = sr0 + i * 32;
    *reinterpret_cast<uint4*>(&Ks[0][swz(r, sc)]) = kreg[i];
    *reinterpret_cast<uint4*>(&Vs[0][swz(r, sc)]) = vreg[i];
  }
  __syncthreads();
  short8 qf0, qf1;
  {
    int r = wave * 16 + l15;
    qf0 = *reinterpret_cast<const short8*>(&QPs[swz(r, quad)]);
    qf1 = *reinterpret_cast<const short8*>(&QPs[swz(r, 4 + quad)]);
  }
  __syncthreads();   // all waves done reading Q before P overwrites QPs

  f32x4 accO[4];
#pragma unroll
  for (int i = 0; i < 4; i++) accO[i] = (f32x4){0.f, 0.f, 0.f, 0.f};
  float rs = 0.f;   // partial row-sum for q-row (wave*16+l15), this lane's keys

  const float SCL = 0.125f * 1.44269504089f;   // 1/sqrt(64) * log2(e)
  const float FM = 13.0f;                      // fixed softmax shift (exact)

  int buf = 0;
  for (int kt = 0; kt <= qt; kt++) {
    if (kt < qt) {
#pragma unroll
      for (int i = 0; i < 2; i++) {
        int r = sr0 + i * 32;
        kreg[i] = *reinterpret_cast<const uint4*>(Kp + (size_t)((kt + 1) * 64 + r) * DKH + sc * 8);
        vreg[i] = *reinterpret_cast<const uint4*>(Vp + (size_t)r * SEQ + (kt + 1) * 64 + sc * 8);
      }
    }

    // S^T = K Q^T : D[m=key][n=qrow]; lane holds keys nb*16+quad*4+{0..3},
    // q-row = wave*16+l15.
    f32x4 sa[4];
    __builtin_amdgcn_s_setprio(1);
#pragma unroll
    for (int nb = 0; nb < 4; nb++) {
      sa[nb] = (f32x4){0.f, 0.f, 0.f, 0.f};
      int r = nb * 16 + l15;
      short8 kf0 = *reinterpret_cast<const short8*>(&Ks[buf][swz(r, quad)]);
      sa[nb] = __builtin_amdgcn_mfma_f32_16x16x32_bf16(kf0, qf0, sa[nb], 0, 0, 0);
      short8 kf1 = *reinterpret_cast<const short8*>(&Ks[buf][swz(r, 4 + quad)]);
      sa[nb] = __builtin_amdgcn_mfma_f32_16x16x32_bf16(kf1, qf1, sa[nb], 0, 0, 0);
    }
    __builtin_amdgcn_s_setprio(0);

    const bool diag = (kt == qt);
    const int prow = wave * 16 + l15;          // this lane's q-row (P row)
#pragma unroll
    for (int nb = 0; nb < 4; nb++) {
      float p0 = exp2f(sa[nb][0] * SCL - FM);
      float p1 = exp2f(sa[nb][1] * SCL - FM);
      float p2 = exp2f(sa[nb][2] * SCL - FM);
      float p3 = exp2f(sa[nb][3] * SCL - FM);
      if (diag) {
        int kbase = nb * 16 + quad * 4;
        if (kbase + 0 > prow) p0 = 0.f;
        if (kbase + 1 > prow) p1 = 0.f;
        if (kbase + 2 > prow) p2 = 0.f;
        if (kbase + 3 > prow) p3 = 0.f;
      }
      rs += (p0 + p1) + (p2 + p3);
      uint2 pk; pk.x = cvtpk(p0, p1); pk.y = cvtpk(p2, p3);
      int g2 = 2 * nb + (quad >> 1);           // granule of keys 16nb+8*(q>>1)
      *reinterpret_cast<uint2*>(&QPs[swz(prow, g2) + (quad & 1) * 4]) = pk;
    }

    // O += P V : A = P (row=qrow=l15, keys u*32+quad*8+..), B = V^T rows
    short8 pf0 = *reinterpret_cast<const short8*>(&QPs[swz(prow, quad)]);
    short8 pf1 = *reinterpret_cast<const short8*>(&QPs[swz(prow, 4 + quad)]);
    __builtin_amdgcn_s_setprio(1);
#pragma unroll
    for (int db = 0; db < 4; db++) {
      int dv = db * 16 + l15;
      short8 vf0 = *reinterpret_cast<const short8*>(&Vs[buf][swz(dv, quad)]);
      accO[db] = __builtin_amdgcn_mfma_f32_16x16x32_bf16(pf0, vf0, accO[db], 0, 0, 0);
      short8 vf1 = *reinterpret_cast<const short8*>(&Vs[buf][swz(dv, 4 + quad)]);
      accO[db] = __builtin_amdgcn_mfma_f32_16x16x32_bf16(pf1, vf1, accO[db], 0, 0, 0);
    }
    __builtin_amdgcn_s_setprio(0);

    if (kt < qt) {
      int nbuf = buf ^ 1;
#pragma unroll
      for (int i = 0; i < 2; i++) {
        int r = sr0 + i * 32;
        *reinterpret_cast<uint4*>(&Ks[nbuf][swz(r, sc)]) = kreg[i];
        *reinterpret_cast<uint4*>(&Vs[nbuf][swz(r, sc)]) = vreg[i];
      }
      __syncthreads();
      buf = nbuf;
    }
  }

  // reduce rs across the 4 quads sharing each l15 (full row sum)
  float t = rs;
  t += __shfl_xor(t, 16);
  t += __shfl_xor(t, 32);
  // accO rows are qrow = quad*4+reg; fetch lrow from lane l15 = quad*4+reg
  float lv[4];
#pragma unroll
  for (int reg = 0; reg < 4; reg++) lv[reg] = __shfl(t, quad * 4 + reg);

  // write (B,S,1024) bf16
  int b = bh >> 4, h = bh & 15;
#pragma unroll
  for (int db = 0; db < 4; db++)
#pragma unroll
    for (int reg = 0; reg < 4; reg++) {
      int s = qt * 64 + wave * 16 + quad * 4 + reg;
      int dv = db * 16 + l15;
      float o = accO[db][reg] / lv[reg];
      Ob[((size_t)(b * SEQ + s)) * DMODEL + h * DKH + dv] = f2bf(o);
    }
}

// ---------------- output projection, 128x64 tile + GLDS (fp32 output) -------
__global__ __launch_bounds__(256) void gemm_out_kernel(
    const short* __restrict__ X, const short* __restrict__ Wo, float* __restrict__ Out) {
  __shared__ __align__(16) short As[128 * 64];
  __shared__ __align__(16) short Bs[64 * 64];
  const int tm = blockIdx.x;   // 32 (M tiles of 128)
  const int tn = blockIdx.y;   // 16 (N tiles of 64)
  const int tid = threadIdx.x;
  const int wave = tid >> 6, lane = tid & 63;
  const int l15 = lane & 15, quad = lane >> 4;
  const int wm = wave >> 1, wn = wave & 1;   // wave tile 64M x 32N

  const short* Abase = X + (size_t)(tm * 128) * DMODEL;
  const short* Bbase = Wo + (size_t)(tn * 64) * DMODEL;

  const int lr = lane >> 3;
  const int lc = (lane & 7) ^ lr;

  f32x4 acc[4][2];
#pragma unroll
  for (int mb = 0; mb < 4; mb++)
#pragma unroll
    for (int nb = 0; nb < 2; nb++) acc[mb][nb] = (f32x4){0.f, 0.f, 0.f, 0.f};

  for (int kk = 0; kk < 16; kk++) {
    const short* Ak = Abase + kk * 64;
    const short* Bk = Bbase + kk * 64;
#pragma unroll
    for (int i = 0; i < 4; i++) {
      int R = i * 32 + wave * 8;
      GLDS16(Ak + (size_t)(R + lr) * DMODEL + lc * 8, &As[R * 64 + lane * 8]);
    }
#pragma unroll
    for (int i = 0; i < 2; i++) {
      int R = i * 32 + wave * 8;
      GLDS16(Bk + (size_t)(R + lr) * DMODEL + lc * 8, &Bs[R * 64 + lane * 8]);
    }
    __syncthreads();
#pragma unroll
    for (int kg = 0; kg < 2; kg++) {
      short8 af[4], bf[2];
#pragma unroll
      for (int mb = 0; mb < 4; mb++) {
        int r = wm * 64 + mb * 16 + l15;
        af[mb] = *reinterpret_cast<const short8*>(&As[swz(r, kg * 4 + quad)]);
      }
#pragma unroll
      for (int nb = 0; nb < 2; nb++) {
        int r = wn * 32 + nb * 16 + l15;
        bf[nb] = *reinterpret_cast<const short8*>(&Bs[swz(r, kg * 4 + quad)]);
      }
#pragma unroll
      for (int mb = 0; mb < 4; mb++)
#pragma unroll
        for (int nb = 0; nb < 2; nb++)
          acc[mb][nb] = __builtin_amdgcn_mfma_f32_16x16x32_bf16(af[mb], bf[nb], acc[mb][nb], 0, 0, 0);
    }
    __syncthreads();
  }
#pragma unroll
  for (int mb = 0; mb < 4; mb++)
#pragma unroll
    for (int nb = 0; nb < 2; nb++)
#pragma unroll
      for (int reg = 0; reg < 4; reg++) {
        int rg = tm * 128 + wm * 64 + mb * 16 + quad * 4 + reg;
        int col = tn * 64 + wn * 32 + nb * 16 + l15;
        Out[(size_t)rg * DMODEL + col] = acc[mb][nb][reg];
      }
}

extern "C" void kernel_launch(void* const* d_in, const int* in_sizes, int n_in,
                              void* d_out, int out_size, void* d_ws, size_t ws_size,
                              hipStream_t stream) {
  (void)in_sizes; (void)n_in; (void)out_size; (void)ws_size;
  const float* X  = (const float*)d_in[0];
  const int*   tp = (const int*)d_in[1];
  const float* Wq = (const float*)d_in[2];
  const float* Wk = (const float*)d_in[3];
  const float* Wv = (const float*)d_in[4];
  const float* Wo = (const float*)d_in[5];
  float* Out = (float*)d_out;

  short* Qb  = (short*)d_ws;           // 4M shorts each
  short* Kb  = Qb + 4194304;
  short* Vb  = Kb + 4194304;           // holds V^T (B,H,D,S)
  short* Ab  = Vb + 4194304;
  short* Xb  = Ab + 4194304;           // 4M
  short* Wqb = Xb + 4194304;           // 1M each; Wqb,Wkb,Wvb CONTIGUOUS
  short* Wkb = Wqb + 1048576;          //   (gemm_qkv treats them as one
  short* Wvb = Wkb + 1048576;          //    3072x1024 concatenated B matrix)
  short* Wob = Wvb + 1048576;
  float* ct  = (float*)(Wob + 1048576);
  float* st  = ct + SEQ * 32;

  precast_rope_kernel<<<dim3(4352), dim3(256), 0, stream>>>(
      X, Wq, Wk, Wv, Wo, tp, Xb, Wqb, Wkb, Wvb, Wob, ct, st);
  gemm_qkv_kernel<<<dim3(256), dim3(512), 0, stream>>>(Xb, Wqb, Wkb, Wvb,
                                                       Qb, Kb, Vb, ct, st);
  attn_kernel<<<dim3(1024), dim3(256), 0, stream>>>(Qb, Kb, Vb, Ab);
  gemm_out_kernel<<<dim3(32, 16), dim3(256), 0, stream>>>(Ab, Wob, Out);
}

// Round 5
// 185.925 us; speedup vs baseline: 1.0653x; 1.0001x over previous
//
#include <hip/hip_runtime.h>
#include <hip/hip_bf16.h>
#include <math.h>

#define NHEADS 16
#define DKH 64
#define SEQ 2048
#define DMODEL 1024

typedef __attribute__((ext_vector_type(8))) short short8;
typedef __attribute__((ext_vector_type(4))) float f32x4;

// async global->LDS, 16B per lane. LDS dest = wave-uniform base + lane*16.
#define GLDS16(g, l)                                         \
  __builtin_amdgcn_global_load_lds(                          \
      (__attribute__((address_space(1))) void*)(void*)(g),   \
      (__attribute__((address_space(3))) void*)(l), 16, 0, 0)

__device__ __forceinline__ short f2bf(float f) {
  unsigned u = __float_as_uint(f);
  unsigned r = (u + 0x7fffu + ((u >> 16) & 1u)) >> 16;
  return (short)r;
}

// packed f32x2 -> bf16x2 in one instruction (RNE on gfx950; T12 recipe).
// D[15:0] = bf16(lo), D[31:16] = bf16(hi).
__device__ __forceinline__ unsigned cvtpk(float lo, float hi) {
  unsigned r;
  asm("v_cvt_pk_bf16_f32 %0, %1, %2" : "=v"(r) : "v"(lo), "v"(hi));
  return r;
}

__device__ __forceinline__ short8 pack8(float4 a, float4 b) {
  short8 v;
  v[0] = f2bf(a.x); v[1] = f2bf(a.y); v[2] = f2bf(a.z); v[3] = f2bf(a.w);
  v[4] = f2bf(b.x); v[5] = f2bf(b.y); v[6] = f2bf(b.z); v[7] = f2bf(b.w);
  return v;
}

// Swizzled LDS tile [rows][64] bf16. Granule = 8 elems (16B).
// Slot gs of row r holds global granule gs ^ (r&7).
__device__ __forceinline__ int swz(int r, int gran) {
  return r * 64 + ((gran ^ (r & 7)) << 3);
}

// ---------------- precast fp32 -> bf16 + RoPE table (merged) ----------------
__global__ __launch_bounds__(256) void precast_rope_kernel(
    const float* __restrict__ X, const float* __restrict__ Wq,
    const float* __restrict__ Wk, const float* __restrict__ Wv,
    const float* __restrict__ Wo, const int* __restrict__ tp,
    short* __restrict__ Xb, short* __restrict__ Wqb, short* __restrict__ Wkb,
    short* __restrict__ Wvb, short* __restrict__ Wob,
    float* __restrict__ ct, float* __restrict__ st) {
  int bid = blockIdx.x;
  if (bid < 4096) {
    int i = bid * 256 + threadIdx.x;
    const float* src; short* dst; int off;
    if (i < 524288) { src = X; dst = Xb; off = i; }
    else {
      int k = i - 524288; int w = k >> 17; off = k & 131071;
      src = (w == 0) ? Wq : (w == 1) ? Wk : (w == 2) ? Wv : Wo;
      dst = (w == 0) ? Wqb : (w == 1) ? Wkb : (w == 2) ? Wvb : Wob;
    }
    const float4* p = reinterpret_cast<const float4*>(src) + 2 * (size_t)off;
    float4 a = p[0], b = p[1];
    reinterpret_cast<short8*>(dst)[off] = pack8(a, b);
  } else {
    int idx = (bid - 4096) * 256 + threadIdx.x;
    if (idx >= SEQ * 32) return;
    int s = idx >> 5, i = idx & 31;
    int is64 = (tp[1] == 0);
    int p = is64 ? tp[2 * s] : tp[s];
    float invf = powf(10000.0f, -(2.0f * (float)i) / 64.0f);
    float a = (float)p * invf;
    ct[idx] = cosf(a);
    st[idx] = sinf(a);
  }
}

// ---------------- fused QKV projection + RoPE -------------------------------
// Round 10: 256x192 tile -> grid 16x16 = 256 blocks = EXACTLY 1 block/CU.
// B = concatenated [Wq;Wk;Wv] as one 3072x1024 matrix; Q/K/V split in epilogue.
// 8-wave (2x4), per-wave 128x48. LDS 112 KiB double-buffered.
// 4 phases/K-tile; steady-state wait = vmcnt(5) once per K-tile.
// Q,K stored (B,H,S,64) with RoPE applied; V stored TRANSPOSED (B,H,64,S).
__global__ __launch_bounds__(512, 2) void gemm_qkv_kernel(
    const short* __restrict__ X, const short* __restrict__ Wq,
    const short* __restrict__ Wk, const short* __restrict__ Wv,
    short* __restrict__ Qb, short* __restrict__ Kb, short* __restrict__ Vb,
    const float* __restrict__ ct, const float* __restrict__ st) {
  __shared__ __align__(16) short As[2][256 * 64];   // 64 KiB
  __shared__ __align__(16) short Bs[2][192 * 64];   // 48 KiB
  const int id = blockIdx.x;
  // XCD-chunked 2D swizzle: xcd = id&7 (round-robin dispatch assumption),
  // each XCD gets a 4(tm) x 8(tn) region. Bijective over 16x16.
  const int xcd = id & 7, rr = id >> 3;
  const int tm = (xcd & 3) * 4 + (rr & 3);
  const int tn = (xcd >> 2) * 8 + (rr >> 2);
  const int tid = threadIdx.x;
  const int wave = tid >> 6, lane = tid & 63;
  const int l15 = lane & 15, quad = lane >> 4;
  const int wm = wave >> 2, wn = wave & 3;   // 2x4 wave grid, 128x48 each

  const int n0 = tn * 192;                   // col in concat [Wq;Wk;Wv]
  const short* Abase = X + (size_t)(tm * 256) * DMODEL;
  const short* Bbase = Wq + (size_t)n0 * DMODEL;   // Wq,Wk,Wv contiguous
  (void)Wk; (void)Wv;

  const int lr = lane >> 3;            // row within 8-row chunk
  const int lc = (lane & 7) ^ lr;      // XOR-permuted source granule

  // A half-tile = 128 rows x 64 k: 2 GLDS/wave (16 rows/wave).
#define STGA(bufi, half, kt_)                                              \
  do {                                                                     \
    int R0 = (half) * 128 + wave * 16;                                     \
    GLDS16(Abase + (size_t)(R0 + lr) * DMODEL + (kt_) * 64 + lc * 8,       \
           &As[bufi][R0 * 64 + lane * 8]);                                 \
    GLDS16(Abase + (size_t)(R0 + 8 + lr) * DMODEL + (kt_) * 64 + lc * 8,   \
           &As[bufi][(R0 + 8) * 64 + lane * 8]);                           \
  } while (0)
  // B third = 64 rows x 64 k: 1 GLDS/wave (8 rows/wave).
#define STGB(bufi, t, kt_)                                                 \
  do {                                                                     \
    int R0 = (t) * 64 + wave * 8;                                          \
    GLDS16(Bbase + (size_t)(R0 + lr) * DMODEL + (kt_) * 64 + lc * 8,       \
           &Bs[bufi][R0 * 64 + lane * 8]);                                 \
  } while (0)

  f32x4 acc[8][3];
#pragma unroll
  for (int m = 0; m < 8; m++)
#pragma unroll
    for (int n = 0; n < 3; n++) acc[m][n] = (f32x4){0.f, 0.f, 0.f, 0.f};

  // prologue: B(0)[3], A0(0)[2], A1(0)[2], B(1)[3] = 10 in flight.
  STGB(0, 0, 0); STGB(0, 1, 0); STGB(0, 2, 0);
  STGA(0, 0, 0); STGA(0, 1, 0);
  STGB(1, 0, 1); STGB(1, 1, 1); STGB(1, 2, 1);

  short8 bfr[3][2];   // B frags live for a whole K-tile (read in phase 0)
  for (int kt = 0; kt < 16; kt++) {
    const int buf = kt & 1;
    // ---- phase 0: stage A-half0(kt+1); wait kt's data; B frags + mf 0,1 ----
    if (kt < 15) { STGA(buf ^ 1, 0, kt + 1); }
    if (kt < 15) { asm volatile("s_waitcnt vmcnt(5)" ::: "memory"); }
    else         { asm volatile("s_waitcnt vmcnt(0)" ::: "memory"); }
    asm volatile("s_barrier" ::: "memory");
#pragma unroll
    for (int nb = 0; nb < 3; nb++)
#pragma unroll
      for (int ks = 0; ks < 2; ks++)
        bfr[nb][ks] = *reinterpret_cast<const short8*>(
            &Bs[buf][swz(wn * 48 + nb * 16 + l15, ks * 4 + quad)]);
    {
      short8 af[2][2];
#pragma unroll
      for (int j = 0; j < 2; j++)
#pragma unroll
        for (int ks = 0; ks < 2; ks++)
          af[j][ks] = *reinterpret_cast<const short8*>(
              &As[buf][swz(wm * 128 + j * 16 + l15, ks * 4 + quad)]);
      __builtin_amdgcn_s_setprio(1);
#pragma unroll
      for (int j = 0; j < 2; j++)
#pragma unroll
        for (int nb = 0; nb < 3; nb++)
#pragma unroll
          for (int ks = 0; ks < 2; ks++)
            acc[j][nb] = __builtin_amdgcn_mfma_f32_16x16x32_bf16(
                af[j][ks], bfr[nb][ks], acc[j][nb], 0, 0, 0);
      __builtin_amdgcn_s_setprio(0);
    }
    asm volatile("s_barrier" ::: "memory");
    // ---- phases 1..3: A frags mf {2p,2p+1}; stage per schedule ------------
#pragma unroll
    for (int p = 1; p < 4; p++) {
      short8 af[2][2];
#pragma unroll
      for (int j = 0; j < 2; j++)
#pragma unroll
        for (int ks = 0; ks < 2; ks++)
          af[j][ks] = *reinterpret_cast<const short8*>(
              &As[buf][swz(wm * 128 + (p * 2 + j) * 16 + l15, ks * 4 + quad)]);
      if (p == 1)      { if (kt < 15) { STGA(buf ^ 1, 1, kt + 1); } }
      else if (p == 2) { if (kt < 14) { STGB(buf, 0, kt + 2); STGB(buf, 1, kt + 2); } }
      else             { if (kt < 14) { STGB(buf, 2, kt + 2); } }
      asm volatile("s_barrier" ::: "memory");
      __builtin_amdgcn_s_setprio(1);
#pragma unroll
      for (int j = 0; j < 2; j++)
#pragma unroll
        for (int nb = 0; nb < 3; nb++)
#pragma unroll
          for (int ks = 0; ks < 2; ks++)
            acc[p * 2 + j][nb] = __builtin_amdgcn_mfma_f32_16x16x32_bf16(
                af[j][ks], bfr[nb][ks], acc[p * 2 + j][nb], 0, 0, 0);
      __builtin_amdgcn_s_setprio(0);
      asm volatile("s_barrier" ::: "memory");
    }
  }
#undef STGA
#undef STGB

  // epilogue: nl is a col of concat [Wq;Wk;Wv]; mid = nl>>10 picks the matrix
#pragma unroll
  for (int mf = 0; mf < 8; mf++) {
    const int s0g = tm * 256 + wm * 128 + mf * 16 + quad * 4;   // rows
    const int b = s0g >> 11, s = s0g & 2047;
#pragma unroll
    for (int nb = 0; nb < 3; nb++) {
      int nl = n0 + wn * 48 + nb * 16 + l15;
      int mid = nl >> 10;                 // 0=Q 1=K 2=V
      int c = nl & 1023;
      int h = c >> 6, dd = c & 63;
      if (mid == 2) {
        // V: packed b64 transposed store -> Vb[(b,h)][dd][s..s+3]
        unsigned u0 = (unsigned)(unsigned short)f2bf(acc[mf][nb][0]) |
                      ((unsigned)(unsigned short)f2bf(acc[mf][nb][1]) << 16);
        unsigned u1 = (unsigned)(unsigned short)f2bf(acc[mf][nb][2]) |
                      ((unsigned)(unsigned short)f2bf(acc[mf][nb][3]) << 16);
        uint2 pk; pk.x = u0; pk.y = u1;
        *reinterpret_cast<uint2*>(Vb + ((size_t)(b * NHEADS + h) * DKH + dd) * SEQ + s) = pk;
      } else {
#pragma unroll
        for (int reg = 0; reg < 4; reg++) {
          float v = acc[mf][nb][reg];
          float pv = __shfl_xor(v, 1);
          int fi = dd >> 1;
          int sg = s + reg;
          float cc = ct[sg * 32 + fi], sn = st[sg * 32 + fi];
          float o = (dd & 1) ? (pv * sn + v * cc) : (v * cc - pv * sn);
          size_t oi = (((size_t)(b * NHEADS + h)) * SEQ + sg) * DKH + dd;
          ((mid == 0) ? Qb : Kb)[oi] = f2bf(o);
        }
      }
    }
  }
}

// ---------------- flash attention (causal), round 13 ------------------------
// Round-12 base (balanced qt map, XCD bh grouping, cvt_pk, setprio) +
// ZERO-SHUFFLE PV: P never touches LDS. MFMA contracts over k-slots with
// identical (lane -> k-slot) maps for A and B operands, so any key
// permutation is legal if BOTH operands use it. S^T leaves lane (quad,l15)
// holding keys {16nb+4*quad+0..3}; the cvt_pk words u[nb],w[nb] already form
// a valid A-frag under sigma(8q+j) = j<4 ? 4q+j : 16+4q+(j-4). V fragments
// are read with the same sigma: two ds_read_b64 per fragment (keys 4q.. and
// 16+4q..). Removes 4 ds_write + 2 ds_read_b128 + lgkm RAW chain per kt and
// ALL P bank conflicts (was 1.08M cycles). Q now loaded per-lane direct from
// global (L2-resident) -> QPs buffer + 2 barriers gone; LDS 40KB -> 32KB.
__global__ __launch_bounds__(256, 4) void attn_kernel(
    const short* __restrict__ Qb, const short* __restrict__ Kb,
    const short* __restrict__ Vtb, short* __restrict__ Ob) {
  __shared__ __align__(16) short Ks[2][64 * 64];   // [key][d]
  __shared__ __align__(16) short Vs[2][64 * 64];   // [dv][key] (from Vtb rows)

  const int id = blockIdx.x;
  const int x8 = id & 7;               // XCD slot (round-robin dispatch)
  const int c  = (id >> 3) & 31;       // CU slot within XCD
  const int q2 = id >> 8;              // co-residency round (0..3)
  const int bh = x8 * 4 + q2;          // 4 consecutive bh per XCD (L2 local)
  const int qt = (q2 == 0) ? c
               : (q2 == 1) ? (31 - c)
               : (q2 == 2) ? ((c + 16) & 31)
               : ((15 - c) & 31);      // per-CU qt sum = 62 for all c

  const int tid = threadIdx.x;
  const int wave = tid >> 6, lane = tid & 63;
  const int l15 = lane & 15, quad = lane >> 4;
  const int sr0 = tid >> 3, sc = tid & 7;

  const short* Qp = Qb + (size_t)bh * SEQ * DKH;
  const short* Kp = Kb + (size_t)bh * SEQ * DKH;
  const short* Vp = Vtb + (size_t)bh * DKH * SEQ;  // rows = dv, cols = s

  uint4 kreg[2], vreg[2];
#pragma unroll
  for (int i = 0; i < 2; i++) {
    int r = sr0 + i * 32;
    kreg[i] = *reinterpret_cast<const uint4*>(Kp + (size_t)r * DKH + sc * 8);
    vreg[i] = *reinterpret_cast<const uint4*>(Vp + (size_t)r * SEQ + sc * 8);
  }
  // Q fragments: per-lane direct global load (row qt*64+wave*16+l15).
  short8 qf0, qf1;
  {
    const short* qrow = Qp + (size_t)(qt * 64 + wave * 16 + l15) * DKH;
    qf0 = *reinterpret_cast<const short8*>(qrow + quad * 8);
    qf1 = *reinterpret_cast<const short8*>(qrow + (4 + quad) * 8);
  }
#pragma unroll
  for (int i = 0; i < 2; i++) {
    int r = sr0 + i * 32;
    *reinterpret_cast<uint4*>(&Ks[0][swz(r, sc)]) = kreg[i];
    *reinterpret_cast<uint4*>(&Vs[0][swz(r, sc)]) = vreg[i];
  }
  __syncthreads();

  f32x4 accO[4];
#pragma unroll
  for (int i = 0; i < 4; i++) accO[i] = (f32x4){0.f, 0.f, 0.f, 0.f};
  float rs = 0.f;   // partial row-sum for q-row (wave*16+l15), this lane's keys

  const float SCL = 0.125f * 1.44269504089f;   // 1/sqrt(64) * log2(e)
  const float FM = 13.0f;                      // fixed softmax shift (exact)

  int buf = 0;
  for (int kt = 0; kt <= qt; kt++) {
    if (kt < qt) {
#pragma unroll
      for (int i = 0; i < 2; i++) {
        int r = sr0 + i * 32;
        kreg[i] = *reinterpret_cast<const uint4*>(Kp + (size_t)((kt + 1) * 64 + r) * DKH + sc * 8);
        vreg[i] = *reinterpret_cast<const uint4*>(Vp + (size_t)r * SEQ + (kt + 1) * 64 + sc * 8);
      }
    }

    // S^T = K Q^T : D[m=key][n=qrow]; lane holds keys nb*16+quad*4+{0..3},
    // q-row = wave*16+l15.
    f32x4 sa[4];
    __builtin_amdgcn_s_setprio(1);
#pragma unroll
    for (int nb = 0; nb < 4; nb++) {
      sa[nb] = (f32x4){0.f, 0.f, 0.f, 0.f};
      int r = nb * 16 + l15;
      short8 kf0 = *reinterpret_cast<const short8*>(&Ks[buf][swz(r, quad)]);
      sa[nb] = __builtin_amdgcn_mfma_f32_16x16x32_bf16(kf0, qf0, sa[nb], 0, 0, 0);
      short8 kf1 = *reinterpret_cast<const short8*>(&Ks[buf][swz(r, 4 + quad)]);
      sa[nb] = __builtin_amdgcn_mfma_f32_16x16x32_bf16(kf1, qf1, sa[nb], 0, 0, 0);
    }
    __builtin_amdgcn_s_setprio(0);

    const bool diag = (kt == qt);
    const int prow = wave * 16 + l15;          // this lane's q-row (P row)
    unsigned pu[4], pw[4];                     // packed P: u=keys 4q+{0,1}, w=+{2,3}
#pragma unroll
    for (int nb = 0; nb < 4; nb++) {
      float p0 = exp2f(sa[nb][0] * SCL - FM);
      float p1 = exp2f(sa[nb][1] * SCL - FM);
      float p2 = exp2f(sa[nb][2] * SCL - FM);
      float p3 = exp2f(sa[nb][3] * SCL - FM);
      if (diag) {
        int kbase = nb * 16 + quad * 4;
        if (kbase + 0 > prow) p0 = 0.f;
        if (kbase + 1 > prow) p1 = 0.f;
        if (kbase + 2 > prow) p2 = 0.f;
        if (kbase + 3 > prow) p3 = 0.f;
      }
      rs += (p0 + p1) + (p2 + p3);
      pu[nb] = cvtpk(p0, p1);
      pw[nb] = cvtpk(p2, p3);
    }

    // O += P V, zero-shuffle: A-frag = packed P as produced; k-slot 8q+j maps
    // key sigma = j<4 ? 4q+j : 16+4q+(j-4) (MFMA#0), +32 (MFMA#1). V B-frag
    // read with same sigma: b64 pairs (keys 4q.., 16+4q..) / (+32, +48).
    short8 pf0, pf1;
    {
      unsigned* w0 = reinterpret_cast<unsigned*>(&pf0);
      w0[0] = pu[0]; w0[1] = pw[0]; w0[2] = pu[1]; w0[3] = pw[1];
      unsigned* w1 = reinterpret_cast<unsigned*>(&pf1);
      w1[0] = pu[2]; w1[1] = pw[2]; w1[2] = pu[3]; w1[3] = pw[3];
    }
    const int qh = quad >> 1, qo = (quad & 1) * 4;   // granule, short offset
    __builtin_amdgcn_s_setprio(1);
#pragma unroll
    for (int db = 0; db < 4; db++) {
      int dv = db * 16 + l15;
      short8 vf0, vf1;
      {
        uint2* v0 = reinterpret_cast<uint2*>(&vf0);
        v0[0] = *reinterpret_cast<const uint2*>(&Vs[buf][swz(dv, qh) + qo]);
        v0[1] = *reinterpret_cast<const uint2*>(&Vs[buf][swz(dv, 2 + qh) + qo]);
        uint2* v1 = reinterpret_cast<uint2*>(&vf1);
        v1[0] = *reinterpret_cast<const uint2*>(&Vs[buf][swz(dv, 4 + qh) + qo]);
        v1[1] = *reinterpret_cast<const uint2*>(&Vs[buf][swz(dv, 6 + qh) + qo]);
      }
      accO[db] = __builtin_amdgcn_mfma_f32_16x16x32_bf16(pf0, vf0, accO[db], 0, 0, 0);
      accO[db] = __builtin_amdgcn_mfma_f32_16x16x32_bf16(pf1, vf1, accO[db], 0, 0, 0);
    }
    __builtin_amdgcn_s_setprio(0);

    if (kt < qt) {
      int nbuf = buf ^ 1;
#pragma unroll
      for (int i = 0; i < 2; i++) {
        int r = sr0 + i * 32;
        *reinterpret_cast<uint4*>(&Ks[nbuf][swz(r, sc)]) = kreg[i];
        *reinterpret_cast<uint4*>(&Vs[nbuf][swz(r, sc)]) = vreg[i];
      }
      __syncthreads();
      buf = nbuf;
    }
  }

  // reduce rs across the 4 quads sharing each l15 (full row sum)
  float t = rs;
  t += __shfl_xor(t, 16);
  t += __shfl_xor(t, 32);
  // accO rows are qrow = quad*4+reg; fetch lrow from lane l15 = quad*4+reg
  float lv[4];
#pragma unroll
  for (int reg = 0; reg < 4; reg++) lv[reg] = __shfl(t, quad * 4 + reg);

  // write (B,S,1024) bf16
  int b = bh >> 4, h = bh & 15;
#pragma unroll
  for (int db = 0; db < 4; db++)
#pragma unroll
    for (int reg = 0; reg < 4; reg++) {
      int s = qt * 64 + wave * 16 + quad * 4 + reg;
      int dv = db * 16 + l15;
      float o = accO[db][reg] / lv[reg];
      Ob[((size_t)(b * SEQ + s)) * DMODEL + h * DKH + dv] = f2bf(o);
    }
}

// ---------------- output projection, 128x64 tile + GLDS (fp32 output) -------
__global__ __launch_bounds__(256) void gemm_out_kernel(
    const short* __restrict__ X, const short* __restrict__ Wo, float* __restrict__ Out) {
  __shared__ __align__(16) short As[128 * 64];
  __shared__ __align__(16) short Bs[64 * 64];
  const int tm = blockIdx.x;   // 32 (M tiles of 128)
  const int tn = blockIdx.y;   // 16 (N tiles of 64)
  const int tid = threadIdx.x;
  const int wave = tid >> 6, lane = tid & 63;
  const int l15 = lane & 15, quad = lane >> 4;
  const int wm = wave >> 1, wn = wave & 1;   // wave tile 64M x 32N

  const short* Abase = X + (size_t)(tm * 128) * DMODEL;
  const short* Bbase = Wo + (size_t)(tn * 64) * DMODEL;

  const int lr = lane >> 3;
  const int lc = (lane & 7) ^ lr;

  f32x4 acc[4][2];
#pragma unroll
  for (int mb = 0; mb < 4; mb++)
#pragma unroll
    for (int nb = 0; nb < 2; nb++) acc[mb][nb] = (f32x4){0.f, 0.f, 0.f, 0.f};

  for (int kk = 0; kk < 16; kk++) {
    const short* Ak = Abase + kk * 64;
    const short* Bk = Bbase + kk * 64;
#pragma unroll
    for (int i = 0; i < 4; i++) {
      int R = i * 32 + wave * 8;
      GLDS16(Ak + (size_t)(R + lr) * DMODEL + lc * 8, &As[R * 64 + lane * 8]);
    }
#pragma unroll
    for (int i = 0; i < 2; i++) {
      int R = i * 32 + wave * 8;
      GLDS16(Bk + (size_t)(R + lr) * DMODEL + lc * 8, &Bs[R * 64 + lane * 8]);
    }
    __syncthreads();
#pragma unroll
    for (int kg = 0; kg < 2; kg++) {
      short8 af[4], bf[2];
#pragma unroll
      for (int mb = 0; mb < 4; mb++) {
        int r = wm * 64 + mb * 16 + l15;
        af[mb] = *reinterpret_cast<const short8*>(&As[swz(r, kg * 4 + quad)]);
      }
#pragma unroll
      for (int nb = 0; nb < 2; nb++) {
        int r = wn * 32 + nb * 16 + l15;
        bf[nb] = *reinterpret_cast<const short8*>(&Bs[swz(r, kg * 4 + quad)]);
      }
#pragma unroll
      for (int mb = 0; mb < 4; mb++)
#pragma unroll
        for (int nb = 0; nb < 2; nb++)
          acc[mb][nb] = __builtin_amdgcn_mfma_f32_16x16x32_bf16(af[mb], bf[nb], acc[mb][nb], 0, 0, 0);
    }
    __syncthreads();
  }
#pragma unroll
  for (int mb = 0; mb < 4; mb++)
#pragma unroll
    for (int nb = 0; nb < 2; nb++)
#pragma unroll
      for (int reg = 0; reg < 4; reg++) {
        int rg = tm * 128 + wm * 64 + mb * 16 + quad * 4 + reg;
        int col = tn * 64 + wn * 32 + nb * 16 + l15;
        Out[(size_t)rg * DMODEL + col] = acc[mb][nb][reg];
      }
}

extern "C" void kernel_launch(void* const* d_in, const int* in_sizes, int n_in,
                              void* d_out, int out_size, void* d_ws, size_t ws_size,
                              hipStream_t stream) {
  (void)in_sizes; (void)n_in; (void)out_size; (void)ws_size;
  const float* X  = (const float*)d_in[0];
  const int*   tp = (const int*)d_in[1];
  const float* Wq = (const float*)d_in[2];
  const float* Wk = (const float*)d_in[3];
  const float* Wv = (const float*)d_in[4];
  const float* Wo = (const float*)d_in[5];
  float* Out = (float*)d_out;

  short* Qb  = (short*)d_ws;           // 4M shorts each
  short* Kb  = Qb + 4194304;
  short* Vb  = Kb + 4194304;           // holds V^T (B,H,D,S)
  short* Ab  = Vb + 4194304;
  short* Xb  = Ab + 4194304;           // 4M
  short* Wqb = Xb + 4194304;           // 1M each; Wqb,Wkb,Wvb CONTIGUOUS
  short* Wkb = Wqb + 1048576;          //   (gemm_qkv treats them as one
  short* Wvb = Wkb + 1048576;          //    3072x1024 concatenated B matrix)
  short* Wob = Wvb + 1048576;
  float* ct  = (float*)(Wob + 1048576);
  float* st  = ct + SEQ * 32;

  precast_rope_kernel<<<dim3(4352), dim3(256), 0, stream>>>(
      X, Wq, Wk, Wv, Wo, tp, Xb, Wqb, Wkb, Wvb, Wob, ct, st);
  gemm_qkv_kernel<<<dim3(256), dim3(512), 0, stream>>>(Xb, Wqb, Wkb, Wvb,
                                                       Qb, Kb, Vb, ct, st);
  attn_kernel<<<dim3(1024), dim3(256), 0, stream>>>(Qb, Kb, Vb, Ab);
  gemm_out_kernel<<<dim3(32, 16), dim3(256), 0, stream>>>(Ab, Wob, Out);
}

// Round 6
// 182.760 us; speedup vs baseline: 1.0838x; 1.0173x over previous
//
#include <hip/hip_runtime.h>
#include <hip/hip_bf16.h>
#include <math.h>

#define NHEADS 16
#define DKH 64
#define SEQ 2048
#define DMODEL 1024

typedef __attribute__((ext_vector_type(8))) short short8;
typedef __attribute__((ext_vector_type(4))) float f32x4;

// async global->LDS, 16B per lane. LDS dest = wave-uniform base + lane*16.
#define GLDS16(g, l)                                         \
  __builtin_amdgcn_global_load_lds(                          \
      (__attribute__((address_space(1))) void*)(void*)(g),   \
      (__attribute__((address_space(3))) void*)(l), 16, 0, 0)

__device__ __forceinline__ short f2bf(float f) {
  unsigned u = __float_as_uint(f);
  unsigned r = (u + 0x7fffu + ((u >> 16) & 1u)) >> 16;
  return (short)r;
}

// packed f32x2 -> bf16x2 in one instruction (RNE on gfx950; T12 recipe).
// D[15:0] = bf16(lo), D[31:16] = bf16(hi).
__device__ __forceinline__ unsigned cvtpk(float lo, float hi) {
  unsigned r;
  asm("v_cvt_pk_bf16_f32 %0, %1, %2" : "=v"(r) : "v"(lo), "v"(hi));
  return r;
}

__device__ __forceinline__ short8 pack8(float4 a, float4 b) {
  short8 v;
  v[0] = f2bf(a.x); v[1] = f2bf(a.y); v[2] = f2bf(a.z); v[3] = f2bf(a.w);
  v[4] = f2bf(b.x); v[5] = f2bf(b.y); v[6] = f2bf(b.z); v[7] = f2bf(b.w);
  return v;
}

// Swizzled LDS tile [rows][64] bf16. Granule = 8 elems (16B).
// Slot gs of row r holds global granule gs ^ (r&7).
__device__ __forceinline__ int swz(int r, int gran) {
  return r * 64 + ((gran ^ (r & 7)) << 3);
}

// ---------------- precast fp32 -> bf16 + RoPE table (merged) ----------------
__global__ __launch_bounds__(256) void precast_rope_kernel(
    const float* __restrict__ X, const float* __restrict__ Wq,
    const float* __restrict__ Wk, const float* __restrict__ Wv,
    const float* __restrict__ Wo, const int* __restrict__ tp,
    short* __restrict__ Xb, short* __restrict__ Wqb, short* __restrict__ Wkb,
    short* __restrict__ Wvb, short* __restrict__ Wob,
    float* __restrict__ ct, float* __restrict__ st) {
  int bid = blockIdx.x;
  if (bid < 4096) {
    int i = bid * 256 + threadIdx.x;
    const float* src; short* dst; int off;
    if (i < 524288) { src = X; dst = Xb; off = i; }
    else {
      int k = i - 524288; int w = k >> 17; off = k & 131071;
      src = (w == 0) ? Wq : (w == 1) ? Wk : (w == 2) ? Wv : Wo;
      dst = (w == 0) ? Wqb : (w == 1) ? Wkb : (w == 2) ? Wvb : Wob;
    }
    const float4* p = reinterpret_cast<const float4*>(src) + 2 * (size_t)off;
    float4 a = p[0], b = p[1];
    reinterpret_cast<short8*>(dst)[off] = pack8(a, b);
  } else {
    int idx = (bid - 4096) * 256 + threadIdx.x;
    if (idx >= SEQ * 32) return;
    int s = idx >> 5, i = idx & 31;
    int is64 = (tp[1] == 0);
    int p = is64 ? tp[2 * s] : tp[s];
    float invf = powf(10000.0f, -(2.0f * (float)i) / 64.0f);
    float a = (float)p * invf;
    ct[idx] = cosf(a);
    st[idx] = sinf(a);
  }
}

// ---------------- fused QKV projection + RoPE -------------------------------
// Round 10: 256x192 tile -> grid 16x16 = 256 blocks = EXACTLY 1 block/CU.
// B = concatenated [Wq;Wk;Wv] as one 3072x1024 matrix; Q/K/V split in epilogue.
// 8-wave (2x4), per-wave 128x48. LDS 112 KiB double-buffered.
// 4 phases/K-tile; steady-state wait = vmcnt(5) once per K-tile.
// Q,K stored (B,H,S,64) with RoPE applied; V stored TRANSPOSED (B,H,64,S).
__global__ __launch_bounds__(512, 2) void gemm_qkv_kernel(
    const short* __restrict__ X, const short* __restrict__ Wq,
    const short* __restrict__ Wk, const short* __restrict__ Wv,
    short* __restrict__ Qb, short* __restrict__ Kb, short* __restrict__ Vb,
    const float* __restrict__ ct, const float* __restrict__ st) {
  __shared__ __align__(16) short As[2][256 * 64];   // 64 KiB
  __shared__ __align__(16) short Bs[2][192 * 64];   // 48 KiB
  const int id = blockIdx.x;
  // XCD-chunked 2D swizzle: xcd = id&7 (round-robin dispatch assumption),
  // each XCD gets a 4(tm) x 8(tn) region. Bijective over 16x16.
  const int xcd = id & 7, rr = id >> 3;
  const int tm = (xcd & 3) * 4 + (rr & 3);
  const int tn = (xcd >> 2) * 8 + (rr >> 2);
  const int tid = threadIdx.x;
  const int wave = tid >> 6, lane = tid & 63;
  const int l15 = lane & 15, quad = lane >> 4;
  const int wm = wave >> 2, wn = wave & 3;   // 2x4 wave grid, 128x48 each

  const int n0 = tn * 192;                   // col in concat [Wq;Wk;Wv]
  const short* Abase = X + (size_t)(tm * 256) * DMODEL;
  const short* Bbase = Wq + (size_t)n0 * DMODEL;   // Wq,Wk,Wv contiguous
  (void)Wk; (void)Wv;

  const int lr = lane >> 3;            // row within 8-row chunk
  const int lc = (lane & 7) ^ lr;      // XOR-permuted source granule

  // A half-tile = 128 rows x 64 k: 2 GLDS/wave (16 rows/wave).
#define STGA(bufi, half, kt_)                                              \
  do {                                                                     \
    int R0 = (half) * 128 + wave * 16;                                     \
    GLDS16(Abase + (size_t)(R0 + lr) * DMODEL + (kt_) * 64 + lc * 8,       \
           &As[bufi][R0 * 64 + lane * 8]);                                 \
    GLDS16(Abase + (size_t)(R0 + 8 + lr) * DMODEL + (kt_) * 64 + lc * 8,   \
           &As[bufi][(R0 + 8) * 64 + lane * 8]);                           \
  } while (0)
  // B third = 64 rows x 64 k: 1 GLDS/wave (8 rows/wave).
#define STGB(bufi, t, kt_)                                                 \
  do {                                                                     \
    int R0 = (t) * 64 + wave * 8;                                          \
    GLDS16(Bbase + (size_t)(R0 + lr) * DMODEL + (kt_) * 64 + lc * 8,       \
           &Bs[bufi][R0 * 64 + lane * 8]);                                 \
  } while (0)

  f32x4 acc[8][3];
#pragma unroll
  for (int m = 0; m < 8; m++)
#pragma unroll
    for (int n = 0; n < 3; n++) acc[m][n] = (f32x4){0.f, 0.f, 0.f, 0.f};

  // prologue: B(0)[3], A0(0)[2], A1(0)[2], B(1)[3] = 10 in flight.
  STGB(0, 0, 0); STGB(0, 1, 0); STGB(0, 2, 0);
  STGA(0, 0, 0); STGA(0, 1, 0);
  STGB(1, 0, 1); STGB(1, 1, 1); STGB(1, 2, 1);

  short8 bfr[3][2];   // B frags live for a whole K-tile (read in phase 0)
  for (int kt = 0; kt < 16; kt++) {
    const int buf = kt & 1;
    // ---- phase 0: stage A-half0(kt+1); wait kt's data; B frags + mf 0,1 ----
    if (kt < 15) { STGA(buf ^ 1, 0, kt + 1); }
    if (kt < 15) { asm volatile("s_waitcnt vmcnt(5)" ::: "memory"); }
    else         { asm volatile("s_waitcnt vmcnt(0)" ::: "memory"); }
    asm volatile("s_barrier" ::: "memory");
#pragma unroll
    for (int nb = 0; nb < 3; nb++)
#pragma unroll
      for (int ks = 0; ks < 2; ks++)
        bfr[nb][ks] = *reinterpret_cast<const short8*>(
            &Bs[buf][swz(wn * 48 + nb * 16 + l15, ks * 4 + quad)]);
    {
      short8 af[2][2];
#pragma unroll
      for (int j = 0; j < 2; j++)
#pragma unroll
        for (int ks = 0; ks < 2; ks++)
          af[j][ks] = *reinterpret_cast<const short8*>(
              &As[buf][swz(wm * 128 + j * 16 + l15, ks * 4 + quad)]);
      __builtin_amdgcn_s_setprio(1);
#pragma unroll
      for (int j = 0; j < 2; j++)
#pragma unroll
        for (int nb = 0; nb < 3; nb++)
#pragma unroll
          for (int ks = 0; ks < 2; ks++)
            acc[j][nb] = __builtin_amdgcn_mfma_f32_16x16x32_bf16(
                af[j][ks], bfr[nb][ks], acc[j][nb], 0, 0, 0);
      __builtin_amdgcn_s_setprio(0);
    }
    asm volatile("s_barrier" ::: "memory");
    // ---- phases 1..3: A frags mf {2p,2p+1}; stage per schedule ------------
#pragma unroll
    for (int p = 1; p < 4; p++) {
      short8 af[2][2];
#pragma unroll
      for (int j = 0; j < 2; j++)
#pragma unroll
        for (int ks = 0; ks < 2; ks++)
          af[j][ks] = *reinterpret_cast<const short8*>(
              &As[buf][swz(wm * 128 + (p * 2 + j) * 16 + l15, ks * 4 + quad)]);
      if (p == 1)      { if (kt < 15) { STGA(buf ^ 1, 1, kt + 1); } }
      else if (p == 2) { if (kt < 14) { STGB(buf, 0, kt + 2); STGB(buf, 1, kt + 2); } }
      else             { if (kt < 14) { STGB(buf, 2, kt + 2); } }
      asm volatile("s_barrier" ::: "memory");
      __builtin_amdgcn_s_setprio(1);
#pragma unroll
      for (int j = 0; j < 2; j++)
#pragma unroll
        for (int nb = 0; nb < 3; nb++)
#pragma unroll
          for (int ks = 0; ks < 2; ks++)
            acc[p * 2 + j][nb] = __builtin_amdgcn_mfma_f32_16x16x32_bf16(
                af[j][ks], bfr[nb][ks], acc[p * 2 + j][nb], 0, 0, 0);
      __builtin_amdgcn_s_setprio(0);
      asm volatile("s_barrier" ::: "memory");
    }
  }
#undef STGA
#undef STGB

  // epilogue: nl is a col of concat [Wq;Wk;Wv]; mid = nl>>10 picks the matrix
#pragma unroll
  for (int mf = 0; mf < 8; mf++) {
    const int s0g = tm * 256 + wm * 128 + mf * 16 + quad * 4;   // rows
    const int b = s0g >> 11, s = s0g & 2047;
#pragma unroll
    for (int nb = 0; nb < 3; nb++) {
      int nl = n0 + wn * 48 + nb * 16 + l15;
      int mid = nl >> 10;                 // 0=Q 1=K 2=V
      int c = nl & 1023;
      int h = c >> 6, dd = c & 63;
      if (mid == 2) {
        // V: packed b64 transposed store -> Vb[(b,h)][dd][s..s+3]
        unsigned u0 = (unsigned)(unsigned short)f2bf(acc[mf][nb][0]) |
                      ((unsigned)(unsigned short)f2bf(acc[mf][nb][1]) << 16);
        unsigned u1 = (unsigned)(unsigned short)f2bf(acc[mf][nb][2]) |
                      ((unsigned)(unsigned short)f2bf(acc[mf][nb][3]) << 16);
        uint2 pk; pk.x = u0; pk.y = u1;
        *reinterpret_cast<uint2*>(Vb + ((size_t)(b * NHEADS + h) * DKH + dd) * SEQ + s) = pk;
      } else {
#pragma unroll
        for (int reg = 0; reg < 4; reg++) {
          float v = acc[mf][nb][reg];
          float pv = __shfl_xor(v, 1);
          int fi = dd >> 1;
          int sg = s + reg;
          float cc = ct[sg * 32 + fi], sn = st[sg * 32 + fi];
          float o = (dd & 1) ? (pv * sn + v * cc) : (v * cc - pv * sn);
          size_t oi = (((size_t)(b * NHEADS + h)) * SEQ + sg) * DKH + dd;
          ((mid == 0) ? Qb : Kb)[oi] = f2bf(o);
        }
      }
    }
  }
}

// ---------------- flash attention (causal), round 14 ------------------------
// Round-13 zero-shuffle PV kept, but V is now SIGMA-STAGED: the key
// permutation sigma (k-slot 8q+j -> key j<4 ? 4q+j : 16+4q+j-4, +32 per MFMA)
// is applied at STAGING time, so the PV V-read is a single ds_read_b128 at
// granule quad / 4+quad -- byte-identical access pattern to the K reads
// (conflict-benign since round 2). Round 13's b64 sigma-reads were a 4-way
// bank conflict (4.3M cycles); this removes them. Staging: each source uint4
// (keys 8sc..8sc+7) splits into two ds_write_b64 halves -> sigma-granules
// ga=4(sc>>2)+2(sc&1), ga+1, slot-half (sc>>1)&1.
__global__ __launch_bounds__(256, 4) void attn_kernel(
    const short* __restrict__ Qb, const short* __restrict__ Kb,
    const short* __restrict__ Vtb, short* __restrict__ Ob) {
  __shared__ __align__(16) short Ks[2][64 * 64];   // [key][d]
  __shared__ __align__(16) short Vs[2][64 * 64];   // [dv][sigma-key]

  const int id = blockIdx.x;
  const int x8 = id & 7;               // XCD slot (round-robin dispatch)
  const int c  = (id >> 3) & 31;       // CU slot within XCD
  const int q2 = id >> 8;              // co-residency round (0..3)
  const int bh = x8 * 4 + q2;          // 4 consecutive bh per XCD (L2 local)
  const int qt = (q2 == 0) ? c
               : (q2 == 1) ? (31 - c)
               : (q2 == 2) ? ((c + 16) & 31)
               : ((15 - c) & 31);      // per-CU qt sum = 62 for all c

  const int tid = threadIdx.x;
  const int wave = tid >> 6, lane = tid & 63;
  const int l15 = lane & 15, quad = lane >> 4;
  const int sr0 = tid >> 3, sc = tid & 7;

  // sigma staging constants for V (per-thread):
  const int vga = ((sc >> 2) << 2) + ((sc & 1) << 1);  // 4m + 2p
  const int vh4 = ((sc >> 1) & 1) * 4;                 // slot-half (shorts)

  const short* Qp = Qb + (size_t)bh * SEQ * DKH;
  const short* Kp = Kb + (size_t)bh * SEQ * DKH;
  const short* Vp = Vtb + (size_t)bh * DKH * SEQ;  // rows = dv, cols = s

  uint4 kreg[2], vreg[2];
#pragma unroll
  for (int i = 0; i < 2; i++) {
    int r = sr0 + i * 32;
    kreg[i] = *reinterpret_cast<const uint4*>(Kp + (size_t)r * DKH + sc * 8);
    vreg[i] = *reinterpret_cast<const uint4*>(Vp + (size_t)r * SEQ + sc * 8);
  }
  // Q fragments: per-lane direct global load (row qt*64+wave*16+l15).
  short8 qf0, qf1;
  {
    const short* qrow = Qp + (size_t)(qt * 64 + wave * 16 + l15) * DKH;
    qf0 = *reinterpret_cast<const short8*>(qrow + quad * 8);
    qf1 = *reinterpret_cast<const short8*>(qrow + (4 + quad) * 8);
  }
#pragma unroll
  for (int i = 0; i < 2; i++) {
    int r = sr0 + i * 32;
    *reinterpret_cast<uint4*>(&Ks[0][swz(r, sc)]) = kreg[i];
    uint2 lo, hi;
    lo.x = vreg[i].x; lo.y = vreg[i].y; hi.x = vreg[i].z; hi.y = vreg[i].w;
    *reinterpret_cast<uint2*>(&Vs[0][swz(r, vga) + vh4]) = lo;
    *reinterpret_cast<uint2*>(&Vs[0][swz(r, vga + 1) + vh4]) = hi;
  }
  __syncthreads();

  f32x4 accO[4];
#pragma unroll
  for (int i = 0; i < 4; i++) accO[i] = (f32x4){0.f, 0.f, 0.f, 0.f};
  float rs = 0.f;   // partial row-sum for q-row (wave*16+l15), this lane's keys

  const float SCL = 0.125f * 1.44269504089f;   // 1/sqrt(64) * log2(e)
  const float FM = 13.0f;                      // fixed softmax shift (exact)

  int buf = 0;
  for (int kt = 0; kt <= qt; kt++) {
    if (kt < qt) {
#pragma unroll
      for (int i = 0; i < 2; i++) {
        int r = sr0 + i * 32;
        kreg[i] = *reinterpret_cast<const uint4*>(Kp + (size_t)((kt + 1) * 64 + r) * DKH + sc * 8);
        vreg[i] = *reinterpret_cast<const uint4*>(Vp + (size_t)r * SEQ + (kt + 1) * 64 + sc * 8);
      }
    }

    // S^T = K Q^T : D[m=key][n=qrow]; lane holds keys nb*16+quad*4+{0..3},
    // q-row = wave*16+l15.
    f32x4 sa[4];
    __builtin_amdgcn_s_setprio(1);
#pragma unroll
    for (int nb = 0; nb < 4; nb++) {
      sa[nb] = (f32x4){0.f, 0.f, 0.f, 0.f};
      int r = nb * 16 + l15;
      short8 kf0 = *reinterpret_cast<const short8*>(&Ks[buf][swz(r, quad)]);
      sa[nb] = __builtin_amdgcn_mfma_f32_16x16x32_bf16(kf0, qf0, sa[nb], 0, 0, 0);
      short8 kf1 = *reinterpret_cast<const short8*>(&Ks[buf][swz(r, 4 + quad)]);
      sa[nb] = __builtin_amdgcn_mfma_f32_16x16x32_bf16(kf1, qf1, sa[nb], 0, 0, 0);
    }
    __builtin_amdgcn_s_setprio(0);

    const bool diag = (kt == qt);
    const int prow = wave * 16 + l15;          // this lane's q-row (P row)
    unsigned pu[4], pw[4];                     // packed P: u=keys 4q+{0,1}, w=+{2,3}
#pragma unroll
    for (int nb = 0; nb < 4; nb++) {
      float p0 = exp2f(sa[nb][0] * SCL - FM);
      float p1 = exp2f(sa[nb][1] * SCL - FM);
      float p2 = exp2f(sa[nb][2] * SCL - FM);
      float p3 = exp2f(sa[nb][3] * SCL - FM);
      if (diag) {
        int kbase = nb * 16 + quad * 4;
        if (kbase + 0 > prow) p0 = 0.f;
        if (kbase + 1 > prow) p1 = 0.f;
        if (kbase + 2 > prow) p2 = 0.f;
        if (kbase + 3 > prow) p3 = 0.f;
      }
      rs += (p0 + p1) + (p2 + p3);
      pu[nb] = cvtpk(p0, p1);
      pw[nb] = cvtpk(p2, p3);
    }

    // O += P V, zero-shuffle: A-frag = packed P as produced (sigma key order);
    // V staged in the SAME sigma order -> single b128 read per fragment at
    // granule quad (keys of nb 0,1) and 4+quad (nb 2,3).
    short8 pf0, pf1;
    {
      unsigned* w0 = reinterpret_cast<unsigned*>(&pf0);
      w0[0] = pu[0]; w0[1] = pw[0]; w0[2] = pu[1]; w0[3] = pw[1];
      unsigned* w1 = reinterpret_cast<unsigned*>(&pf1);
      w1[0] = pu[2]; w1[1] = pw[2]; w1[2] = pu[3]; w1[3] = pw[3];
    }
    __builtin_amdgcn_s_setprio(1);
#pragma unroll
    for (int db = 0; db < 4; db++) {
      int dv = db * 16 + l15;
      short8 vf0 = *reinterpret_cast<const short8*>(&Vs[buf][swz(dv, quad)]);
      accO[db] = __builtin_amdgcn_mfma_f32_16x16x32_bf16(pf0, vf0, accO[db], 0, 0, 0);
      short8 vf1 = *reinterpret_cast<const short8*>(&Vs[buf][swz(dv, 4 + quad)]);
      accO[db] = __builtin_amdgcn_mfma_f32_16x16x32_bf16(pf1, vf1, accO[db], 0, 0, 0);
    }
    __builtin_amdgcn_s_setprio(0);

    if (kt < qt) {
      int nbuf = buf ^ 1;
#pragma unroll
      for (int i = 0; i < 2; i++) {
        int r = sr0 + i * 32;
        *reinterpret_cast<uint4*>(&Ks[nbuf][swz(r, sc)]) = kreg[i];
        uint2 lo, hi;
        lo.x = vreg[i].x; lo.y = vreg[i].y; hi.x = vreg[i].z; hi.y = vreg[i].w;
        *reinterpret_cast<uint2*>(&Vs[nbuf][swz(r, vga) + vh4]) = lo;
        *reinterpret_cast<uint2*>(&Vs[nbuf][swz(r, vga + 1) + vh4]) = hi;
      }
      __syncthreads();
      buf = nbuf;
    }
  }

  // reduce rs across the 4 quads sharing each l15 (full row sum)
  float t = rs;
  t += __shfl_xor(t, 16);
  t += __shfl_xor(t, 32);
  // accO rows are qrow = quad*4+reg; fetch lrow from lane l15 = quad*4+reg
  float lv[4];
#pragma unroll
  for (int reg = 0; reg < 4; reg++) lv[reg] = __shfl(t, quad * 4 + reg);

  // write (B,S,1024) bf16
  int b = bh >> 4, h = bh & 15;
#pragma unroll
  for (int db = 0; db < 4; db++)
#pragma unroll
    for (int reg = 0; reg < 4; reg++) {
      int s = qt * 64 + wave * 16 + quad * 4 + reg;
      int dv = db * 16 + l15;
      float o = accO[db][reg] / lv[reg];
      Ob[((size_t)(b * SEQ + s)) * DMODEL + h * DKH + dv] = f2bf(o);
    }
}

// ---------------- output projection, 128x64 tile + GLDS (fp32 output) -------
__global__ __launch_bounds__(256) void gemm_out_kernel(
    const short* __restrict__ X, const short* __restrict__ Wo, float* __restrict__ Out) {
  __shared__ __align__(16) short As[128 * 64];
  __shared__ __align__(16) short Bs[64 * 64];
  const int tm = blockIdx.x;   // 32 (M tiles of 128)
  const int tn = blockIdx.y;   // 16 (N tiles of 64)
  const int tid = threadIdx.x;
  const int wave = tid >> 6, lane = tid & 63;
  const int l15 = lane & 15, quad = lane >> 4;
  const int wm = wave >> 1, wn = wave & 1;   // wave tile 64M x 32N

  const short* Abase = X + (size_t)(tm * 128) * DMODEL;
  const short* Bbase = Wo + (size_t)(tn * 64) * DMODEL;

  const int lr = lane >> 3;
  const int lc = (lane & 7) ^ lr;

  f32x4 acc[4][2];
#pragma unroll
  for (int mb = 0; mb < 4; mb++)
#pragma unroll
    for (int nb = 0; nb < 2; nb++) acc[mb][nb] = (f32x4){0.f, 0.f, 0.f, 0.f};

  for (int kk = 0; kk < 16; kk++) {
    const short* Ak = Abase + kk * 64;
    const short* Bk = Bbase + kk * 64;
#pragma unroll
    for (int i = 0; i < 4; i++) {
      int R = i * 32 + wave * 8;
      GLDS16(Ak + (size_t)(R + lr) * DMODEL + lc * 8, &As[R * 64 + lane * 8]);
    }
#pragma unroll
    for (int i = 0; i < 2; i++) {
      int R = i * 32 + wave * 8;
      GLDS16(Bk + (size_t)(R + lr) * DMODEL + lc * 8, &Bs[R * 64 + lane * 8]);
    }
    __syncthreads();
#pragma unroll
    for (int kg = 0; kg < 2; kg++) {
      short8 af[4], bf[2];
#pragma unroll
      for (int mb = 0; mb < 4; mb++) {
        int r = wm * 64 + mb * 16 + l15;
        af[mb] = *reinterpret_cast<const short8*>(&As[swz(r, kg * 4 + quad)]);
      }
#pragma unroll
      for (int nb = 0; nb < 2; nb++) {
        int r = wn * 32 + nb * 16 + l15;
        bf[nb] = *reinterpret_cast<const short8*>(&Bs[swz(r, kg * 4 + quad)]);
      }
#pragma unroll
      for (int mb = 0; mb < 4; mb++)
#pragma unroll
        for (int nb = 0; nb < 2; nb++)
          acc[mb][nb] = __builtin_amdgcn_mfma_f32_16x16x32_bf16(af[mb], bf[nb], acc[mb][nb], 0, 0, 0);
    }
    __syncthreads();
  }
#pragma unroll
  for (int mb = 0; mb < 4; mb++)
#pragma unroll
    for (int nb = 0; nb < 2; nb++)
#pragma unroll
      for (int reg = 0; reg < 4; reg++) {
        int rg = tm * 128 + wm * 64 + mb * 16 + quad * 4 + reg;
        int col = tn * 64 + wn * 32 + nb * 16 + l15;
        Out[(size_t)rg * DMODEL + col] = acc[mb][nb][reg];
      }
}

extern "C" void kernel_launch(void* const* d_in, const int* in_sizes, int n_in,
                              void* d_out, int out_size, void* d_ws, size_t ws_size,
                              hipStream_t stream) {
  (void)in_sizes; (void)n_in; (void)out_size; (void)ws_size;
  const float* X  = (const float*)d_in[0];
  const int*   tp = (const int*)d_in[1];
  const float* Wq = (const float*)d_in[2];
  const float* Wk = (const float*)d_in[3];
  const float* Wv = (const float*)d_in[4];
  const float* Wo = (const float*)d_in[5];
  float* Out = (float*)d_out;

  short* Qb  = (short*)d_ws;           // 4M shorts each
  short* Kb  = Qb + 4194304;
  short* Vb  = Kb + 4194304;           // holds V^T (B,H,D,S)
  short* Ab  = Vb + 4194304;
  short* Xb  = Ab + 4194304;           // 4M
  short* Wqb = Xb + 4194304;           // 1M each; Wqb,Wkb,Wvb CONTIGUOUS
  short* Wkb = Wqb + 1048576;          //   (gemm_qkv treats them as one
  short* Wvb = Wkb + 1048576;          //    3072x1024 concatenated B matrix)
  short* Wob = Wvb + 1048576;
  float* ct  = (float*)(Wob + 1048576);
  float* st  = ct + SEQ * 32;

  precast_rope_kernel<<<dim3(4352), dim3(256), 0, stream>>>(
      X, Wq, Wk, Wv, Wo, tp, Xb, Wqb, Wkb, Wvb, Wob, ct, st);
  gemm_qkv_kernel<<<dim3(256), dim3(512), 0, stream>>>(Xb, Wqb, Wkb, Wvb,
                                                       Qb, Kb, Vb, ct, st);
  attn_kernel<<<dim3(1024), dim3(256), 0, stream>>>(Qb, Kb, Vb, Ab);
  gemm_out_kernel<<<dim3(32, 16), dim3(256), 0, stream>>>(Ab, Wob, Out);
}

// Round 7
// 181.521 us; speedup vs baseline: 1.0912x; 1.0068x over previous
//
#include <hip/hip_runtime.h>
#include <hip/hip_bf16.h>
#include <math.h>

#define NHEADS 16
#define DKH 64
#define SEQ 2048
#define DMODEL 1024

typedef __attribute__((ext_vector_type(8))) short short8;
typedef __attribute__((ext_vector_type(4))) float f32x4;

// async global->LDS, 16B per lane. LDS dest = wave-uniform base + lane*16.
#define GLDS16(g, l)                                         \
  __builtin_amdgcn_global_load_lds(                          \
      (__attribute__((address_space(1))) void*)(void*)(g),   \
      (__attribute__((address_space(3))) void*)(l), 16, 0, 0)

__device__ __forceinline__ short f2bf(float f) {
  unsigned u = __float_as_uint(f);
  unsigned r = (u + 0x7fffu + ((u >> 16) & 1u)) >> 16;
  return (short)r;
}

// packed f32x2 -> bf16x2 in one instruction (RNE on gfx950; T12 recipe).
__device__ __forceinline__ unsigned cvtpk(float lo, float hi) {
  unsigned r;
  asm("v_cvt_pk_bf16_f32 %0, %1, %2" : "=v"(r) : "v"(lo), "v"(hi));
  return r;
}

__device__ __forceinline__ short8 pack8(float4 a, float4 b) {
  short8 v;
  v[0] = f2bf(a.x); v[1] = f2bf(a.y); v[2] = f2bf(a.z); v[3] = f2bf(a.w);
  v[4] = f2bf(b.x); v[5] = f2bf(b.y); v[6] = f2bf(b.z); v[7] = f2bf(b.w);
  return v;
}

// Swizzled LDS tile [rows][64] bf16. Granule = 8 elems (16B).
// Slot gs of row r holds global granule gs ^ (r&7).
__device__ __forceinline__ int swz(int r, int gran) {
  return r * 64 + ((gran ^ (r & 7)) << 3);
}

// ---------------- precast fp32 -> bf16 + RoPE table (merged) ----------------
__global__ __launch_bounds__(256) void precast_rope_kernel(
    const float* __restrict__ X, const float* __restrict__ Wq,
    const float* __restrict__ Wk, const float* __restrict__ Wv,
    const float* __restrict__ Wo, const int* __restrict__ tp,
    short* __restrict__ Xb, short* __restrict__ Wqb, short* __restrict__ Wkb,
    short* __restrict__ Wvb, short* __restrict__ Wob,
    float* __restrict__ ct, float* __restrict__ st) {
  int bid = blockIdx.x;
  if (bid < 4096) {
    int i = bid * 256 + threadIdx.x;
    const float* src; short* dst; int off;
    if (i < 524288) { src = X; dst = Xb; off = i; }
    else {
      int k = i - 524288; int w = k >> 17; off = k & 131071;
      src = (w == 0) ? Wq : (w == 1) ? Wk : (w == 2) ? Wv : Wo;
      dst = (w == 0) ? Wqb : (w == 1) ? Wkb : (w == 2) ? Wvb : Wob;
    }
    const float4* p = reinterpret_cast<const float4*>(src) + 2 * (size_t)off;
    float4 a = p[0], b = p[1];
    reinterpret_cast<short8*>(dst)[off] = pack8(a, b);
  } else {
    int idx = (bid - 4096) * 256 + threadIdx.x;
    if (idx >= SEQ * 32) return;
    int s = idx >> 5, i = idx & 31;
    int is64 = (tp[1] == 0);
    int p = is64 ? tp[2 * s] : tp[s];
    float invf = powf(10000.0f, -(2.0f * (float)i) / 64.0f);
    float a = (float)p * invf;
    ct[idx] = cosf(a);
    st[idx] = sinf(a);
  }
}

// ---------------- fused QKV projection + RoPE -------------------------------
// Round 15: TLP-first hybrid. Evidence: every 1-block/CU deep-pipeline
// variant stalled ~85% (MfmaUtil 14, VALU 11, HBM 4%); best qkv so far was
// r0's 3-blocks/CU 2-phase (51.4). m114: cross-block wave overlap captures
// what source pipelining adds -- so keep TLP AND remove the vmcnt(0) drain.
// 128x192 tile, grid 32x16 = 512 blocks = EXACTLY 2/CU (LDS 80 KiB x2 = 160).
// 256 thr / 4 waves (1Mx4N), per-wave 128x48, acc[8][3].
// 2 barriers per K-tile (not 8); steady-state s_waitcnt vmcnt(10)
// (= next K-tile's A[4]+B[6] GLDS in flight), vmcnt(0) only at last tile.
// B = concat [Wq;Wk;Wv] (contiguous workspace); Q/K/V split in epilogue.
// Q,K stored (B,H,S,64) with RoPE applied; V stored TRANSPOSED (B,H,64,S).
__global__ __launch_bounds__(256, 2) void gemm_qkv_kernel(
    const short* __restrict__ X, const short* __restrict__ Wq,
    const short* __restrict__ Wk, const short* __restrict__ Wv,
    short* __restrict__ Qb, short* __restrict__ Kb, short* __restrict__ Vb,
    const float* __restrict__ ct, const float* __restrict__ st) {
  __shared__ __align__(16) short As[2][128 * 64];   // 32 KiB
  __shared__ __align__(16) short Bs[2][192 * 64];   // 48 KiB
  const int id = blockIdx.x;           // 512 blocks
  const int tm = id >> 4;              // 32 M-tiles of 128
  const int tn = id & 15;              // 16 N-tiles of 192 across concat B
  const int tid = threadIdx.x;
  const int wave = tid >> 6, lane = tid & 63;
  const int l15 = lane & 15, quad = lane >> 4;

  const int n0 = tn * 192;                         // col in concat [Wq;Wk;Wv]
  const short* Abase = X + (size_t)(tm * 128) * DMODEL;
  const short* Bbase = Wq + (size_t)n0 * DMODEL;   // Wq,Wk,Wv contiguous
  (void)Wk; (void)Wv;

  const int lr = lane >> 3;            // row within 8-row chunk
  const int lc = (lane & 7) ^ lr;      // XOR-permuted source granule

  // Stage one K-tile (A 128x64 = 4 GLDS/wave, B 192x64 = 6 GLDS/wave).
#define STG(kt_, bufi)                                                     \
  do {                                                                     \
    _Pragma("unroll")                                                      \
    for (int i2 = 0; i2 < 4; i2++) {                                       \
      int R0 = i2 * 32 + wave * 8;                                         \
      GLDS16(Abase + (size_t)(R0 + lr) * DMODEL + (kt_) * 64 + lc * 8,     \
             &As[bufi][R0 * 64 + lane * 8]);                               \
    }                                                                      \
    _Pragma("unroll")                                                      \
    for (int i2 = 0; i2 < 6; i2++) {                                       \
      int R0 = i2 * 32 + wave * 8;                                         \
      GLDS16(Bbase + (size_t)(R0 + lr) * DMODEL + (kt_) * 64 + lc * 8,     \
             &Bs[bufi][R0 * 64 + lane * 8]);                               \
    }                                                                      \
  } while (0)

  f32x4 acc[8][3];
#pragma unroll
  for (int m = 0; m < 8; m++)
#pragma unroll
    for (int n = 0; n < 3; n++) acc[m][n] = (f32x4){0.f, 0.f, 0.f, 0.f};

  STG(0, 0);   // prologue: 10 in flight
  for (int kt = 0; kt < 16; kt++) {
    const int buf = kt & 1;
    if (kt < 15) { STG(kt + 1, buf ^ 1); }      // 10 more in flight
    if (kt < 15) { asm volatile("s_waitcnt vmcnt(10)" ::: "memory"); }
    else         { asm volatile("s_waitcnt vmcnt(0)" ::: "memory"); }
    asm volatile("s_barrier" ::: "memory");     // all waves' kt data resident
#pragma unroll
    for (int ks = 0; ks < 2; ks++) {
      short8 bfr[3], af[8];
#pragma unroll
      for (int nb = 0; nb < 3; nb++)
        bfr[nb] = *reinterpret_cast<const short8*>(
            &Bs[buf][swz(wave * 48 + nb * 16 + l15, ks * 4 + quad)]);
#pragma unroll
      for (int mf = 0; mf < 8; mf++)
        af[mf] = *reinterpret_cast<const short8*>(
            &As[buf][swz(mf * 16 + l15, ks * 4 + quad)]);
      __builtin_amdgcn_s_setprio(1);
#pragma unroll
      for (int mf = 0; mf < 8; mf++)
#pragma unroll
        for (int nb = 0; nb < 3; nb++)
          acc[mf][nb] = __builtin_amdgcn_mfma_f32_16x16x32_bf16(
              af[mf], bfr[nb], acc[mf][nb], 0, 0, 0);
      __builtin_amdgcn_s_setprio(0);
    }
    asm volatile("s_barrier" ::: "memory");     // all waves done reading buf
  }
#undef STG

  // epilogue: nl is a col of concat [Wq;Wk;Wv]; mid = nl>>10 picks the matrix
#pragma unroll
  for (int mf = 0; mf < 8; mf++) {
    const int s0g = tm * 128 + mf * 16 + quad * 4;   // rows
    const int b = s0g >> 11, s = s0g & 2047;
#pragma unroll
    for (int nb = 0; nb < 3; nb++) {
      int nl = n0 + wave * 48 + nb * 16 + l15;
      int mid = nl >> 10;                 // 0=Q 1=K 2=V
      int c = nl & 1023;
      int h = c >> 6, dd = c & 63;
      if (mid == 2) {
        // V: packed b64 transposed store -> Vb[(b,h)][dd][s..s+3]
        unsigned u0 = (unsigned)(unsigned short)f2bf(acc[mf][nb][0]) |
                      ((unsigned)(unsigned short)f2bf(acc[mf][nb][1]) << 16);
        unsigned u1 = (unsigned)(unsigned short)f2bf(acc[mf][nb][2]) |
                      ((unsigned)(unsigned short)f2bf(acc[mf][nb][3]) << 16);
        uint2 pk; pk.x = u0; pk.y = u1;
        *reinterpret_cast<uint2*>(Vb + ((size_t)(b * NHEADS + h) * DKH + dd) * SEQ + s) = pk;
      } else {
#pragma unroll
        for (int reg = 0; reg < 4; reg++) {
          float v = acc[mf][nb][reg];
          float pv = __shfl_xor(v, 1);
          int fi = dd >> 1;
          int sg = s + reg;
          float cc = ct[sg * 32 + fi], sn = st[sg * 32 + fi];
          float o = (dd & 1) ? (pv * sn + v * cc) : (v * cc - pv * sn);
          size_t oi = (((size_t)(b * NHEADS + h)) * SEQ + sg) * DKH + dd;
          ((mid == 0) ? Qb : Kb)[oi] = f2bf(o);
        }
      }
    }
  }
}

// ---------------- flash attention (causal), round 14 (unchanged) ------------
// Zero-shuffle PV with SIGMA-STAGED V: key permutation sigma applied at
// staging, so PV V-read is a single ds_read_b128 at granule quad / 4+quad
// (conflict-benign, same pattern as K reads). Balanced qt map + XCD bh
// grouping + cvt_pk + setprio.
__global__ __launch_bounds__(256, 4) void attn_kernel(
    const short* __restrict__ Qb, const short* __restrict__ Kb,
    const short* __restrict__ Vtb, short* __restrict__ Ob) {
  __shared__ __align__(16) short Ks[2][64 * 64];   // [key][d]
  __shared__ __align__(16) short Vs[2][64 * 64];   // [dv][sigma-key]

  const int id = blockIdx.x;
  const int x8 = id & 7;               // XCD slot (round-robin dispatch)
  const int c  = (id >> 3) & 31;       // CU slot within XCD
  const int q2 = id >> 8;              // co-residency round (0..3)
  const int bh = x8 * 4 + q2;          // 4 consecutive bh per XCD (L2 local)
  const int qt = (q2 == 0) ? c
               : (q2 == 1) ? (31 - c)
               : (q2 == 2) ? ((c + 16) & 31)
               : ((15 - c) & 31);      // per-CU qt sum = 62 for all c

  const int tid = threadIdx.x;
  const int wave = tid >> 6, lane = tid & 63;
  const int l15 = lane & 15, quad = lane >> 4;
  const int sr0 = tid >> 3, sc = tid & 7;

  // sigma staging constants for V (per-thread):
  const int vga = ((sc >> 2) << 2) + ((sc & 1) << 1);  // 4m + 2p
  const int vh4 = ((sc >> 1) & 1) * 4;                 // slot-half (shorts)

  const short* Qp = Qb + (size_t)bh * SEQ * DKH;
  const short* Kp = Kb + (size_t)bh * SEQ * DKH;
  const short* Vp = Vtb + (size_t)bh * DKH * SEQ;  // rows = dv, cols = s

  uint4 kreg[2], vreg[2];
#pragma unroll
  for (int i = 0; i < 2; i++) {
    int r = sr0 + i * 32;
    kreg[i] = *reinterpret_cast<const uint4*>(Kp + (size_t)r * DKH + sc * 8);
    vreg[i] = *reinterpret_cast<const uint4*>(Vp + (size_t)r * SEQ + sc * 8);
  }
  // Q fragments: per-lane direct global load (row qt*64+wave*16+l15).
  short8 qf0, qf1;
  {
    const short* qrow = Qp + (size_t)(qt * 64 + wave * 16 + l15) * DKH;
    qf0 = *reinterpret_cast<const short8*>(qrow + quad * 8);
    qf1 = *reinterpret_cast<const short8*>(qrow + (4 + quad) * 8);
  }
#pragma unroll
  for (int i = 0; i < 2; i++) {
    int r = sr0 + i * 32;
    *reinterpret_cast<uint4*>(&Ks[0][swz(r, sc)]) = kreg[i];
    uint2 lo, hi;
    lo.x = vreg[i].x; lo.y = vreg[i].y; hi.x = vreg[i].z; hi.y = vreg[i].w;
    *reinterpret_cast<uint2*>(&Vs[0][swz(r, vga) + vh4]) = lo;
    *reinterpret_cast<uint2*>(&Vs[0][swz(r, vga + 1) + vh4]) = hi;
  }
  __syncthreads();

  f32x4 accO[4];
#pragma unroll
  for (int i = 0; i < 4; i++) accO[i] = (f32x4){0.f, 0.f, 0.f, 0.f};
  float rs = 0.f;   // partial row-sum for q-row (wave*16+l15), this lane's keys

  const float SCL = 0.125f * 1.44269504089f;   // 1/sqrt(64) * log2(e)
  const float FM = 13.0f;                      // fixed softmax shift (exact)

  int buf = 0;
  for (int kt = 0; kt <= qt; kt++) {
    if (kt < qt) {
#pragma unroll
      for (int i = 0; i < 2; i++) {
        int r = sr0 + i * 32;
        kreg[i] = *reinterpret_cast<const uint4*>(Kp + (size_t)((kt + 1) * 64 + r) * DKH + sc * 8);
        vreg[i] = *reinterpret_cast<const uint4*>(Vp + (size_t)r * SEQ + (kt + 1) * 64 + sc * 8);
      }
    }

    // S^T = K Q^T : D[m=key][n=qrow]; lane holds keys nb*16+quad*4+{0..3},
    // q-row = wave*16+l15.
    f32x4 sa[4];
    __builtin_amdgcn_s_setprio(1);
#pragma unroll
    for (int nb = 0; nb < 4; nb++) {
      sa[nb] = (f32x4){0.f, 0.f, 0.f, 0.f};
      int r = nb * 16 + l15;
      short8 kf0 = *reinterpret_cast<const short8*>(&Ks[buf][swz(r, quad)]);
      sa[nb] = __builtin_amdgcn_mfma_f32_16x16x32_bf16(kf0, qf0, sa[nb], 0, 0, 0);
      short8 kf1 = *reinterpret_cast<const short8*>(&Ks[buf][swz(r, 4 + quad)]);
      sa[nb] = __builtin_amdgcn_mfma_f32_16x16x32_bf16(kf1, qf1, sa[nb], 0, 0, 0);
    }
    __builtin_amdgcn_s_setprio(0);

    const bool diag = (kt == qt);
    const int prow = wave * 16 + l15;          // this lane's q-row (P row)
    unsigned pu[4], pw[4];                     // packed P: u=keys 4q+{0,1}, w=+{2,3}
#pragma unroll
    for (int nb = 0; nb < 4; nb++) {
      float p0 = exp2f(sa[nb][0] * SCL - FM);
      float p1 = exp2f(sa[nb][1] * SCL - FM);
      float p2 = exp2f(sa[nb][2] * SCL - FM);
      float p3 = exp2f(sa[nb][3] * SCL - FM);
      if (diag) {
        int kbase = nb * 16 + quad * 4;
        if (kbase + 0 > prow) p0 = 0.f;
        if (kbase + 1 > prow) p1 = 0.f;
        if (kbase + 2 > prow) p2 = 0.f;
        if (kbase + 3 > prow) p3 = 0.f;
      }
      rs += (p0 + p1) + (p2 + p3);
      pu[nb] = cvtpk(p0, p1);
      pw[nb] = cvtpk(p2, p3);
    }

    // O += P V, zero-shuffle: A-frag = packed P as produced (sigma key order);
    // V staged in the SAME sigma order -> single b128 read per fragment at
    // granule quad (keys of nb 0,1) and 4+quad (nb 2,3).
    short8 pf0, pf1;
    {
      unsigned* w0 = reinterpret_cast<unsigned*>(&pf0);
      w0[0] = pu[0]; w0[1] = pw[0]; w0[2] = pu[1]; w0[3] = pw[1];
      unsigned* w1 = reinterpret_cast<unsigned*>(&pf1);
      w1[0] = pu[2]; w1[1] = pw[2]; w1[2] = pu[3]; w1[3] = pw[3];
    }
    __builtin_amdgcn_s_setprio(1);
#pragma unroll
    for (int db = 0; db < 4; db++) {
      int dv = db * 16 + l15;
      short8 vf0 = *reinterpret_cast<const short8*>(&Vs[buf][swz(dv, quad)]);
      accO[db] = __builtin_amdgcn_mfma_f32_16x16x32_bf16(pf0, vf0, accO[db], 0, 0, 0);
      short8 vf1 = *reinterpret_cast<const short8*>(&Vs[buf][swz(dv, 4 + quad)]);
      accO[db] = __builtin_amdgcn_mfma_f32_16x16x32_bf16(pf1, vf1, accO[db], 0, 0, 0);
    }
    __builtin_amdgcn_s_setprio(0);

    if (kt < qt) {
      int nbuf = buf ^ 1;
#pragma unroll
      for (int i = 0; i < 2; i++) {
        int r = sr0 + i * 32;
        *reinterpret_cast<uint4*>(&Ks[nbuf][swz(r, sc)]) = kreg[i];
        uint2 lo, hi;
        lo.x = vreg[i].x; lo.y = vreg[i].y; hi.x = vreg[i].z; hi.y = vreg[i].w;
        *reinterpret_cast<uint2*>(&Vs[nbuf][swz(r, vga) + vh4]) = lo;
        *reinterpret_cast<uint2*>(&Vs[nbuf][swz(r, vga + 1) + vh4]) = hi;
      }
      __syncthreads();
      buf = nbuf;
    }
  }

  // reduce rs across the 4 quads sharing each l15 (full row sum)
  float t = rs;
  t += __shfl_xor(t, 16);
  t += __shfl_xor(t, 32);
  // accO rows are qrow = quad*4+reg; fetch lrow from lane l15 = quad*4+reg
  float lv[4];
#pragma unroll
  for (int reg = 0; reg < 4; reg++) lv[reg] = __shfl(t, quad * 4 + reg);

  // write (B,S,1024) bf16
  int b = bh >> 4, h = bh & 15;
#pragma unroll
  for (int db = 0; db < 4; db++)
#pragma unroll
    for (int reg = 0; reg < 4; reg++) {
      int s = qt * 64 + wave * 16 + quad * 4 + reg;
      int dv = db * 16 + l15;
      float o = accO[db][reg] / lv[reg];
      Ob[((size_t)(b * SEQ + s)) * DMODEL + h * DKH + dv] = f2bf(o);
    }
}

// ---------------- output projection, 128x64 tile + GLDS (fp32 output) -------
__global__ __launch_bounds__(256) void gemm_out_kernel(
    const short* __restrict__ X, const short* __restrict__ Wo, float* __restrict__ Out) {
  __shared__ __align__(16) short As[128 * 64];
  __shared__ __align__(16) short Bs[64 * 64];
  const int tm = blockIdx.x;   // 32 (M tiles of 128)
  const int tn = blockIdx.y;   // 16 (N tiles of 64)
  const int tid = threadIdx.x;
  const int wave = tid >> 6, lane = tid & 63;
  const int l15 = lane & 15, quad = lane >> 4;
  const int wm = wave >> 1, wn = wave & 1;   // wave tile 64M x 32N

  const short* Abase = X + (size_t)(tm * 128) * DMODEL;
  const short* Bbase = Wo + (size_t)(tn * 64) * DMODEL;

  const int lr = lane >> 3;
  const int lc = (lane & 7) ^ lr;

  f32x4 acc[4][2];
#pragma unroll
  for (int mb = 0; mb < 4; mb++)
#pragma unroll
    for (int nb = 0; nb < 2; nb++) acc[mb][nb] = (f32x4){0.f, 0.f, 0.f, 0.f};

  for (int kk = 0; kk < 16; kk++) {
    const short* Ak = Abase + kk * 64;
    const short* Bk = Bbase + kk * 64;
#pragma unroll
    for (int i = 0; i < 4; i++) {
      int R = i * 32 + wave * 8;
      GLDS16(Ak + (size_t)(R + lr) * DMODEL + lc * 8, &As[R * 64 + lane * 8]);
    }
#pragma unroll
    for (int i = 0; i < 2; i++) {
      int R = i * 32 + wave * 8;
      GLDS16(Bk + (size_t)(R + lr) * DMODEL + lc * 8, &Bs[R * 64 + lane * 8]);
    }
    __syncthreads();
#pragma unroll
    for (int kg = 0; kg < 2; kg++) {
      short8 af[4], bf[2];
#pragma unroll
      for (int mb = 0; mb < 4; mb++) {
        int r = wm * 64 + mb * 16 + l15;
        af[mb] = *reinterpret_cast<const short8*>(&As[swz(r, kg * 4 + quad)]);
      }
#pragma unroll
      for (int nb = 0; nb < 2; nb++) {
        int r = wn * 32 + nb * 16 + l15;
        bf[nb] = *reinterpret_cast<const short8*>(&Bs[swz(r, kg * 4 + quad)]);
      }
#pragma unroll
      for (int mb = 0; mb < 4; mb++)
#pragma unroll
        for (int nb = 0; nb < 2; nb++)
          acc[mb][nb] = __builtin_amdgcn_mfma_f32_16x16x32_bf16(af[mb], bf[nb], acc[mb][nb], 0, 0, 0);
    }
    __syncthreads();
  }
#pragma unroll
  for (int mb = 0; mb < 4; mb++)
#pragma unroll
    for (int nb = 0; nb < 2; nb++)
#pragma unroll
      for (int reg = 0; reg < 4; reg++) {
        int rg = tm * 128 + wm * 64 + mb * 16 + quad * 4 + reg;
        int col = tn * 64 + wn * 32 + nb * 16 + l15;
        Out[(size_t)rg * DMODEL + col] = acc[mb][nb][reg];
      }
}

extern "C" void kernel_launch(void* const* d_in, const int* in_sizes, int n_in,
                              void* d_out, int out_size, void* d_ws, size_t ws_size,
                              hipStream_t stream) {
  (void)in_sizes; (void)n_in; (void)out_size; (void)ws_size;
  const float* X  = (const float*)d_in[0];
  const int*   tp = (const int*)d_in[1];
  const float* Wq = (const float*)d_in[2];
  const float* Wk = (const float*)d_in[3];
  const float* Wv = (const float*)d_in[4];
  const float* Wo = (const float*)d_in[5];
  float* Out = (float*)d_out;

  short* Qb  = (short*)d_ws;           // 4M shorts each
  short* Kb  = Qb + 4194304;
  short* Vb  = Kb + 4194304;           // holds V^T (B,H,D,S)
  short* Ab  = Vb + 4194304;
  short* Xb  = Ab + 4194304;           // 4M
  short* Wqb = Xb + 4194304;           // 1M each; Wqb,Wkb,Wvb CONTIGUOUS
  short* Wkb = Wqb + 1048576;          //   (gemm_qkv treats them as one
  short* Wvb = Wkb + 1048576;          //    3072x1024 concatenated B matrix)
  short* Wob = Wvb + 1048576;
  float* ct  = (float*)(Wob + 1048576);
  float* st  = ct + SEQ * 32;

  precast_rope_kernel<<<dim3(4352), dim3(256), 0, stream>>>(
      X, Wq, Wk, Wv, Wo, tp, Xb, Wqb, Wkb, Wvb, Wob, ct, st);
  gemm_qkv_kernel<<<dim3(512), dim3(256), 0, stream>>>(Xb, Wqb, Wkb, Wvb,
                                                       Qb, Kb, Vb, ct, st);
  attn_kernel<<<dim3(1024), dim3(256), 0, stream>>>(Qb, Kb, Vb, Ab);
  gemm_out_kernel<<<dim3(32, 16), dim3(256), 0, stream>>>(Ab, Wob, Out);
}